// Round 4
// baseline (4627.423 us; speedup 1.0000x reference)
//
#include <hip/hip_runtime.h>
#include <math.h>

#define NN 169343
#define NE 1166243
#define FF 128
#define NC 40

static inline int cdiv(long long a, long long b){ return (int)((a + b - 1) / b); }

// ---------------- degree / normalization ----------------

__global__ void k_fill(float* __restrict__ p, float v, int n){
    int i = blockIdx.x * 256 + threadIdx.x;
    if (i < n) p[i] = v;
}

__global__ void k_count(const int* __restrict__ dst, float* __restrict__ deg, int E){
    int i = blockIdx.x * 256 + threadIdx.x;
    if (i < E) atomicAdd(&deg[dst[i]], 1.0f);
}

__global__ void k_rsqrt(float* __restrict__ d, int n){
    int i = blockIdx.x * 256 + threadIdx.x;
    if (i < n) d[i] = rsqrtf(d[i]);   // deg >= 1 always (self loop)
}

// ---------------- GEMM: out[M][128] = A[M][128] @ W[128][128] ----------------
// 64-row block tile, K chunked by 32 into LDS, 256 thr = 32 col-thr x 8 row-thr,
// per-thread 8 rows x 4 cols.

__global__ __launch_bounds__(256) void k_gemm128(const float* __restrict__ A,
                                                 const float* __restrict__ W,
                                                 float* __restrict__ out, int M){
    __shared__ float Ash[64][32];
    __shared__ float Wsh[32][128];
    const int tid = threadIdx.x;
    const int ct = tid & 31, rt = tid >> 5;
    const int c0 = ct * 4;
    const int row0 = blockIdx.x * 64;
    float acc[8][4] = {};
    for (int kc = 0; kc < 128; kc += 32){
        __syncthreads();
#pragma unroll
        for (int i = 0; i < 2; i++){
            int q = tid + 256 * i; int r = q >> 3; int c4 = (q & 7) * 4;
            int gr = row0 + r;
            float4 v = {0.f, 0.f, 0.f, 0.f};
            if (gr < M) v = *(const float4*)&A[(size_t)gr * FF + kc + c4];
            *(float4*)&Ash[r][c4] = v;
        }
#pragma unroll
        for (int i = 0; i < 4; i++){
            int q = tid + 256 * i; int r = q >> 5; int c4 = (q & 31) * 4;
            *(float4*)&Wsh[r][c4] = *(const float4*)&W[(size_t)(kc + r) * FF + c4];
        }
        __syncthreads();
#pragma unroll
        for (int k4 = 0; k4 < 32; k4 += 4){
            float4 w0 = *(const float4*)&Wsh[k4 + 0][c0];
            float4 w1 = *(const float4*)&Wsh[k4 + 1][c0];
            float4 w2 = *(const float4*)&Wsh[k4 + 2][c0];
            float4 w3 = *(const float4*)&Wsh[k4 + 3][c0];
#pragma unroll
            for (int i = 0; i < 8; i++){
                float4 a = *(const float4*)&Ash[rt * 8 + i][k4];
                acc[i][0] = fmaf(a.w,w3.x, fmaf(a.z,w2.x, fmaf(a.y,w1.x, fmaf(a.x,w0.x, acc[i][0]))));
                acc[i][1] = fmaf(a.w,w3.y, fmaf(a.z,w2.y, fmaf(a.y,w1.y, fmaf(a.x,w0.y, acc[i][1]))));
                acc[i][2] = fmaf(a.w,w3.z, fmaf(a.z,w2.z, fmaf(a.y,w1.z, fmaf(a.x,w0.z, acc[i][2]))));
                acc[i][3] = fmaf(a.w,w3.w, fmaf(a.z,w2.w, fmaf(a.y,w1.w, fmaf(a.x,w0.w, acc[i][3]))));
            }
        }
    }
#pragma unroll
    for (int i = 0; i < 8; i++){
        int gr = row0 + rt * 8 + i;
        if (gr < M){
            float4 v = {acc[i][0], acc[i][1], acc[i][2], acc[i][3]};
            *(float4*)&out[(size_t)gr * FF + c0] = v;
        }
    }
}

// ---------------- GEMM: out[M][40] = A[M][128] @ W[128][40] ----------------
// Whole W (20KB) + 32 A-rows (padded stride 132) in LDS. 256 thr = 32 rows x 8 col-thr,
// per-thread 5 contiguous cols.

__global__ __launch_bounds__(256) void k_gemm40(const float* __restrict__ A,
                                                const float* __restrict__ W,
                                                float* __restrict__ out, int M){
    __shared__ float Wsh[128][40];
    __shared__ float Ash[32][132];
    const int tid = threadIdx.x;
    const int rt = tid >> 3, ct = tid & 7;
    const int cb = ct * 5;
    const int row0 = blockIdx.x * 32;
#pragma unroll
    for (int i = 0; i < 5; i++){
        int q = tid + 256 * i;            // 1280 float4 total
        int r = q / 10, c4 = (q % 10) * 4;
        *(float4*)&Wsh[r][c4] = *(const float4*)&W[(size_t)r * NC + c4];
    }
#pragma unroll
    for (int i = 0; i < 4; i++){
        int q = tid + 256 * i; int r = q >> 5, c4 = (q & 31) * 4;
        int gr = row0 + r;
        float4 v = {0.f, 0.f, 0.f, 0.f};
        if (gr < M) v = *(const float4*)&A[(size_t)gr * FF + c4];
        *(float4*)&Ash[r][c4] = v;
    }
    __syncthreads();
    float acc[5] = {};
    for (int k4 = 0; k4 < 128; k4 += 4){
        float4 a = *(const float4*)&Ash[rt][k4];
#pragma unroll
        for (int j = 0; j < 5; j++){
            acc[j] = fmaf(a.x, Wsh[k4 + 0][cb + j], acc[j]);
            acc[j] = fmaf(a.y, Wsh[k4 + 1][cb + j], acc[j]);
            acc[j] = fmaf(a.z, Wsh[k4 + 2][cb + j], acc[j]);
            acc[j] = fmaf(a.w, Wsh[k4 + 3][cb + j], acc[j]);
        }
    }
    int gr = row0 + rt;
    if (gr < M){
#pragma unroll
        for (int j = 0; j < 5; j++) out[(size_t)gr * NC + cb + j] = acc[j];
    }
}

// ---------------- aggregation (A_hat @ H), 128-wide ----------------

__global__ void k_self128(const float* __restrict__ H, const float* __restrict__ dinv,
                          float* __restrict__ AGG, int n){
    int i = blockIdx.x * 256 + threadIdx.x;      // over n*32 float4s
    if (i >= n * 32) return;
    int v = i >> 5, q = i & 31;
    float d = dinv[v]; float s = d * d;
    float4 h = *(const float4*)&H[(size_t)v * FF + q * 4];
    float4 o = {h.x * s, h.y * s, h.z * s, h.w * s};
    *(float4*)&AGG[(size_t)v * FF + q * 4] = o;
}

__global__ void k_edge128(const int* __restrict__ S, const int* __restrict__ D,
                          const float* __restrict__ dinv, const float* __restrict__ H,
                          float* __restrict__ AGG, int E){
    int i = blockIdx.x * 256 + threadIdx.x;      // over E*32 (37.3M, fits int)
    if (i >= E * 32) return;
    int e = i >> 5, q = i & 31;
    int s = S[e], d = D[e];
    float w = dinv[s] * dinv[d];
    float4 h = *(const float4*)&H[(size_t)s * FF + q * 4];
    float* o = &AGG[(size_t)d * FF + q * 4];
    atomicAdd(o + 0, h.x * w);
    atomicAdd(o + 1, h.y * w);
    atomicAdd(o + 2, h.z * w);
    atomicAdd(o + 3, h.w * w);
}

template<int RELU>
__global__ void k_bias128(float* __restrict__ X, const float* __restrict__ b, int n){
    int i = blockIdx.x * 256 + threadIdx.x;      // over n*32 float4s
    if (i >= n * 32) return;
    int q = i & 31;
    float4 v = *(float4*)&X[(size_t)i * 4];
    float4 bb = *(const float4*)&b[q * 4];
    v.x += bb.x; v.y += bb.y; v.z += bb.z; v.w += bb.w;
    if (RELU){
        v.x = fmaxf(v.x, 0.f); v.y = fmaxf(v.y, 0.f);
        v.z = fmaxf(v.z, 0.f); v.w = fmaxf(v.w, 0.f);
    }
    *(float4*)&X[(size_t)i * 4] = v;
}

// ---------------- aggregation, 40-wide (into d_out) ----------------

__global__ void k_self40(const float* __restrict__ H, const float* __restrict__ dinv,
                         float* __restrict__ AGG, int n){
    int i = blockIdx.x * 256 + threadIdx.x;      // over n*40
    if (i >= n * NC) return;
    unsigned v = (unsigned)i / 40u;
    float d = dinv[v];
    AGG[i] = H[i] * d * d;
}

__global__ void k_edge40(const int* __restrict__ S, const int* __restrict__ D,
                         const float* __restrict__ dinv, const float* __restrict__ H,
                         float* __restrict__ AGG, int E){
    int i = blockIdx.x * 256 + threadIdx.x;      // over E*40 (46.6M, fits int)
    if (i >= E * NC) return;
    unsigned e = (unsigned)i / 40u, f = (unsigned)i % 40u;
    int s = S[e], d = D[e];
    float w = dinv[s] * dinv[d];
    atomicAdd(&AGG[(size_t)d * NC + f], H[(size_t)s * NC + f] * w);
}

// ---------------- bias + log_softmax over 40 classes, one wave per row ----------------

__global__ __launch_bounds__(256) void k_lsm(float* __restrict__ out, const float* __restrict__ b, int n){
    int gt = blockIdx.x * 256 + threadIdx.x;
    int wid = gt >> 6;            // wave id = row
    int lane = gt & 63;
    if (wid >= n) return;         // wave-uniform exit
    float* row = out + (size_t)wid * NC;
    float val = 0.f, m = -INFINITY;
    if (lane < NC){ val = row[lane] + b[lane]; m = val; }
#pragma unroll
    for (int off = 32; off; off >>= 1) m = fmaxf(m, __shfl_xor(m, off));
    float ex = (lane < NC) ? expf(val - m) : 0.f;
    float sm = ex;
#pragma unroll
    for (int off = 32; off; off >>= 1) sm += __shfl_xor(sm, off);
    float ls = logf(sm);
    if (lane < NC) row[lane] = val - m - ls;
}

// ---------------- launch ----------------

extern "C" void kernel_launch(void* const* d_in, const int* in_sizes, int n_in,
                              void* d_out, int out_size, void* d_ws, size_t ws_size,
                              hipStream_t stream){
    const float* x  = (const float*)d_in[0];
    const int*   ei = (const int*)d_in[1];     // [2, NE] int32
    const float* W1 = (const float*)d_in[2];
    const float* b1 = (const float*)d_in[3];
    const float* W2 = (const float*)d_in[4];
    const float* b2 = (const float*)d_in[5];
    const float* W3 = (const float*)d_in[6];
    const float* b3 = (const float*)d_in[7];
    const int* S = ei;
    const int* D = ei + NE;
    float* out = (float*)d_out;

    float* ws   = (float*)d_ws;
    float* dinv = ws;                          // NN floats (padded to 169344)
    float* A    = ws + 169344;                 // NN*128
    float* B    = A + (size_t)NN * FF;         // NN*128
    float* H3   = A;                           // NN*40, reuses A

    dim3 blk(256);

    // normalization
    k_fill  <<<cdiv(NN, 256), blk, 0, stream>>>(dinv, 1.0f, NN);
    k_count <<<cdiv(NE, 256), blk, 0, stream>>>(D, dinv, NE);
    k_rsqrt <<<cdiv(NN, 256), blk, 0, stream>>>(dinv, NN);

    // layer 1: A = x@W1 ; B = Ahat*A ; B = relu(B + b1)
    k_gemm128 <<<cdiv(NN, 64), blk, 0, stream>>>(x, W1, A, NN);
    k_self128 <<<cdiv((long long)NN * 32, 256), blk, 0, stream>>>(A, dinv, B, NN);
    k_edge128 <<<cdiv((long long)NE * 32, 256), blk, 0, stream>>>(S, D, dinv, A, B, NE);
    k_bias128<1> <<<cdiv((long long)NN * 32, 256), blk, 0, stream>>>(B, b1, NN);

    // layer 2: A = B@W2 ; B = Ahat*A ; B = B + b2
    k_gemm128 <<<cdiv(NN, 64), blk, 0, stream>>>(B, W2, A, NN);
    k_self128 <<<cdiv((long long)NN * 32, 256), blk, 0, stream>>>(A, dinv, B, NN);
    k_edge128 <<<cdiv((long long)NE * 32, 256), blk, 0, stream>>>(S, D, dinv, A, B, NE);
    k_bias128<0> <<<cdiv((long long)NN * 32, 256), blk, 0, stream>>>(B, b2, NN);

    // layer 3: H3 = B@W3 ; out = Ahat*H3 ; out = log_softmax(out + b3)
    k_gemm40 <<<cdiv(NN, 32), blk, 0, stream>>>(B, W3, H3, NN);
    k_self40 <<<cdiv((long long)NN * NC, 256), blk, 0, stream>>>(H3, dinv, out, NN);
    k_edge40 <<<cdiv((long long)NE * NC, 256), blk, 0, stream>>>(S, D, dinv, H3, out, NE);
    k_lsm    <<<cdiv(NN, 4), blk, 0, stream>>>(out, b3, NN);
}

// Round 5
// 894.968 us; speedup vs baseline: 5.1705x; 5.1705x over previous
//
#include <hip/hip_runtime.h>
#include <math.h>

#define NN 169343
#define NE 1166243
#define FF 128
#define NC 40
#define NB_SCAN 166   // cdiv(NN, 1024)

static inline int cdiv(long long a, long long b){ return (int)((a + b - 1) / b); }

// ================= CSR build =================

__global__ void k_zeroi(int* __restrict__ p, int n){
    int i = blockIdx.x * 256 + threadIdx.x;
    if (i < n) p[i] = 0;
}

__global__ void k_hist(const int* __restrict__ D, int* __restrict__ cnt, int E){
    int e = blockIdx.x * 256 + threadIdx.x;
    if (e < E) atomicAdd(&cnt[D[e]], 1);
}

__global__ void k_dinv(float* __restrict__ dinv, const int* __restrict__ cnt, int n){
    int i = blockIdx.x * 256 + threadIdx.x;
    if (i < n) dinv[i] = rsqrtf((float)(cnt[i] + 1));   // +1 self loop
}

// block b sums cnt[b*1024 .. b*1024+1023]
__global__ __launch_bounds__(256) void k_blksum(const int* __restrict__ cnt, int* __restrict__ bsum){
    __shared__ int wsum[4];
    int t = threadIdx.x;
    int base = blockIdx.x * 1024 + t * 4;
    int s = 0;
#pragma unroll
    for (int j = 0; j < 4; j++) if (base + j < NN) s += cnt[base + j];
#pragma unroll
    for (int off = 32; off; off >>= 1) s += __shfl_down(s, off);
    if ((t & 63) == 0) wsum[t >> 6] = s;
    __syncthreads();
    if (t == 0) bsum[blockIdx.x] = wsum[0] + wsum[1] + wsum[2] + wsum[3];
}

// single block: exclusive scan of bsum[nb] (nb <= 256)
__global__ __launch_bounds__(256) void k_scan_root(int* __restrict__ bsum, int nb){
    __shared__ int sh[256];
    int t = threadIdx.x;
    int v = (t < nb) ? bsum[t] : 0;
    sh[t] = v; __syncthreads();
    for (int d = 1; d < 256; d <<= 1){
        int add = (t >= d) ? sh[t - d] : 0;
        __syncthreads();
        sh[t] += add;
        __syncthreads();
    }
    if (t < nb) bsum[t] = sh[t] - v;   // exclusive
}

__global__ __launch_bounds__(256) void k_scan_final(const int* __restrict__ cnt,
                                                    const int* __restrict__ bsumEx,
                                                    int* __restrict__ rowptr){
    __shared__ int sh[256];
    int t = threadIdx.x;
    int base = blockIdx.x * 1024 + t * 4;
    int v0=0,v1=0,v2=0,v3=0;
    if (base + 0 < NN) v0 = cnt[base + 0];
    if (base + 1 < NN) v1 = cnt[base + 1];
    if (base + 2 < NN) v2 = cnt[base + 2];
    if (base + 3 < NN) v3 = cnt[base + 3];
    int tsum = v0 + v1 + v2 + v3;
    sh[t] = tsum; __syncthreads();
    for (int d = 1; d < 256; d <<= 1){
        int add = (t >= d) ? sh[t - d] : 0;
        __syncthreads();
        sh[t] += add;
        __syncthreads();
    }
    int off = sh[t] - tsum + bsumEx[blockIdx.x];
    if (base + 0 < NN) rowptr[base + 0] = off;
    if (base + 1 < NN) rowptr[base + 1] = off + v0;
    if (base + 2 < NN) rowptr[base + 2] = off + v0 + v1;
    if (base + 3 < NN) rowptr[base + 3] = off + v0 + v1 + v2;
}

__global__ void k_fillpos(const int* __restrict__ rowptr, int* __restrict__ pos, int n){
    int i = blockIdx.x * 256 + threadIdx.x;
    if (i < n) pos[i] = rowptr[i];
    if (i == 0) ((int*)rowptr)[NN] = NE;   // sentinel
}

__global__ void k_scatter(const int* __restrict__ S, const int* __restrict__ D,
                          const float* __restrict__ dinv, int* __restrict__ pos,
                          int* __restrict__ srcs, float* __restrict__ wns, int E){
    int e = blockIdx.x * 256 + threadIdx.x;
    if (e >= E) return;
    int s = S[e], d = D[e];
    int p = atomicAdd(&pos[d], 1);
    srcs[p] = s;
    wns[p] = dinv[s] * dinv[d];
}

// ================= GEMMs (unchanged from round 4) =================

__global__ __launch_bounds__(256) void k_gemm128(const float* __restrict__ A,
                                                 const float* __restrict__ W,
                                                 float* __restrict__ out, int M){
    __shared__ float Ash[64][32];
    __shared__ float Wsh[32][128];
    const int tid = threadIdx.x;
    const int ct = tid & 31, rt = tid >> 5;
    const int c0 = ct * 4;
    const int row0 = blockIdx.x * 64;
    float acc[8][4] = {};
    for (int kc = 0; kc < 128; kc += 32){
        __syncthreads();
#pragma unroll
        for (int i = 0; i < 2; i++){
            int q = tid + 256 * i; int r = q >> 3; int c4 = (q & 7) * 4;
            int gr = row0 + r;
            float4 v = {0.f, 0.f, 0.f, 0.f};
            if (gr < M) v = *(const float4*)&A[(size_t)gr * FF + kc + c4];
            *(float4*)&Ash[r][c4] = v;
        }
#pragma unroll
        for (int i = 0; i < 4; i++){
            int q = tid + 256 * i; int r = q >> 5; int c4 = (q & 31) * 4;
            *(float4*)&Wsh[r][c4] = *(const float4*)&W[(size_t)(kc + r) * FF + c4];
        }
        __syncthreads();
#pragma unroll
        for (int k4 = 0; k4 < 32; k4 += 4){
            float4 w0 = *(const float4*)&Wsh[k4 + 0][c0];
            float4 w1 = *(const float4*)&Wsh[k4 + 1][c0];
            float4 w2 = *(const float4*)&Wsh[k4 + 2][c0];
            float4 w3 = *(const float4*)&Wsh[k4 + 3][c0];
#pragma unroll
            for (int i = 0; i < 8; i++){
                float4 a = *(const float4*)&Ash[rt * 8 + i][k4];
                acc[i][0] = fmaf(a.w,w3.x, fmaf(a.z,w2.x, fmaf(a.y,w1.x, fmaf(a.x,w0.x, acc[i][0]))));
                acc[i][1] = fmaf(a.w,w3.y, fmaf(a.z,w2.y, fmaf(a.y,w1.y, fmaf(a.x,w0.y, acc[i][1]))));
                acc[i][2] = fmaf(a.w,w3.z, fmaf(a.z,w2.z, fmaf(a.y,w1.z, fmaf(a.x,w0.z, acc[i][2]))));
                acc[i][3] = fmaf(a.w,w3.w, fmaf(a.z,w2.w, fmaf(a.y,w1.w, fmaf(a.x,w0.w, acc[i][3]))));
            }
        }
    }
#pragma unroll
    for (int i = 0; i < 8; i++){
        int gr = row0 + rt * 8 + i;
        if (gr < M){
            float4 v = {acc[i][0], acc[i][1], acc[i][2], acc[i][3]};
            *(float4*)&out[(size_t)gr * FF + c0] = v;
        }
    }
}

__global__ __launch_bounds__(256) void k_gemm40(const float* __restrict__ A,
                                                const float* __restrict__ W,
                                                float* __restrict__ out, int M){
    __shared__ float Wsh[128][40];
    __shared__ float Ash[32][132];
    const int tid = threadIdx.x;
    const int rt = tid >> 3, ct = tid & 7;
    const int cb = ct * 5;
    const int row0 = blockIdx.x * 32;
#pragma unroll
    for (int i = 0; i < 5; i++){
        int q = tid + 256 * i;
        int r = q / 10, c4 = (q % 10) * 4;
        *(float4*)&Wsh[r][c4] = *(const float4*)&W[(size_t)r * NC + c4];
    }
#pragma unroll
    for (int i = 0; i < 4; i++){
        int q = tid + 256 * i; int r = q >> 5, c4 = (q & 31) * 4;
        int gr = row0 + r;
        float4 v = {0.f, 0.f, 0.f, 0.f};
        if (gr < M) v = *(const float4*)&A[(size_t)gr * FF + c4];
        *(float4*)&Ash[r][c4] = v;
    }
    __syncthreads();
    float acc[5] = {};
    for (int k4 = 0; k4 < 128; k4 += 4){
        float4 a = *(const float4*)&Ash[rt][k4];
#pragma unroll
        for (int j = 0; j < 5; j++){
            acc[j] = fmaf(a.x, Wsh[k4 + 0][cb + j], acc[j]);
            acc[j] = fmaf(a.y, Wsh[k4 + 1][cb + j], acc[j]);
            acc[j] = fmaf(a.z, Wsh[k4 + 2][cb + j], acc[j]);
            acc[j] = fmaf(a.w, Wsh[k4 + 3][cb + j], acc[j]);
        }
    }
    int gr = row0 + rt;
    if (gr < M){
#pragma unroll
        for (int j = 0; j < 5; j++) out[(size_t)gr * NC + cb + j] = acc[j];
    }
}

// ================= CSR gather aggregation =================
// One wave per destination row; lane l owns cols [2l, 2l+1].
// OUT[v] = act( sum_{e in row v} H[srcs[e]]*wns[e] + dinv[v]^2 * H[v] + bias )

template<int RELU>
__global__ __launch_bounds__(256) void k_agg128(const float* __restrict__ H,
                                                const float* __restrict__ dinv,
                                                const int* __restrict__ rowptr,
                                                const int* __restrict__ srcs,
                                                const float* __restrict__ wns,
                                                const float* __restrict__ bias,
                                                float* __restrict__ OUT){
    int wv = (blockIdx.x * 256 + threadIdx.x) >> 6;   // global wave id = row
    int lane = threadIdx.x & 63;
    if (wv >= NN) return;                             // wave-uniform exit
    int r0 = rowptr[wv], r1 = rowptr[wv + 1];
    float dv = dinv[wv];
    float sw = dv * dv;
    float2 acc = *(const float2*)&H[(size_t)wv * FF + lane * 2];
    acc.x *= sw; acc.y *= sw;
    for (int e = r0; e < r1; ++e){
        int s = srcs[e];
        float wn = wns[e];
        float2 h = *(const float2*)&H[(size_t)s * FF + lane * 2];
        acc.x = fmaf(h.x, wn, acc.x);
        acc.y = fmaf(h.y, wn, acc.y);
    }
    float2 bb = *(const float2*)&bias[lane * 2];
    acc.x += bb.x; acc.y += bb.y;
    if (RELU){ acc.x = fmaxf(acc.x, 0.f); acc.y = fmaxf(acc.y, 0.f); }
    *(float2*)&OUT[(size_t)wv * FF + lane * 2] = acc;
}

// 40-wide gather + bias + log_softmax, fused. One wave per row, lanes 0..39 active.
__global__ __launch_bounds__(256) void k_agg40lsm(const float* __restrict__ H,
                                                  const float* __restrict__ dinv,
                                                  const int* __restrict__ rowptr,
                                                  const int* __restrict__ srcs,
                                                  const float* __restrict__ wns,
                                                  const float* __restrict__ bias,
                                                  float* __restrict__ OUT){
    int wv = (blockIdx.x * 256 + threadIdx.x) >> 6;
    int lane = threadIdx.x & 63;
    if (wv >= NN) return;
    int r0 = rowptr[wv], r1 = rowptr[wv + 1];
    float dv = dinv[wv];
    float acc = 0.f;
    if (lane < NC) acc = H[(size_t)wv * NC + lane] * dv * dv;
    for (int e = r0; e < r1; ++e){
        int s = srcs[e];
        float wn = wns[e];
        if (lane < NC) acc = fmaf(H[(size_t)s * NC + lane], wn, acc);
    }
    float val = (lane < NC) ? acc + bias[lane] : -INFINITY;
    float m = val;
#pragma unroll
    for (int off = 32; off; off >>= 1) m = fmaxf(m, __shfl_xor(m, off));
    float ex = (lane < NC) ? expf(val - m) : 0.f;
    float sm = ex;
#pragma unroll
    for (int off = 32; off; off >>= 1) sm += __shfl_xor(sm, off);
    float ls = logf(sm);
    if (lane < NC) OUT[(size_t)wv * NC + lane] = val - m - ls;
}

// ================= launch =================

extern "C" void kernel_launch(void* const* d_in, const int* in_sizes, int n_in,
                              void* d_out, int out_size, void* d_ws, size_t ws_size,
                              hipStream_t stream){
    const float* x  = (const float*)d_in[0];
    const int*   ei = (const int*)d_in[1];
    const float* W1 = (const float*)d_in[2];
    const float* b1 = (const float*)d_in[3];
    const float* W2 = (const float*)d_in[4];
    const float* b2 = (const float*)d_in[5];
    const float* W3 = (const float*)d_in[6];
    const float* b3 = (const float*)d_in[7];
    const int* S = ei;
    const int* D = ei + NE;
    float* out = (float*)d_out;

    // workspace layout (units of 4B). NN+1 == 169344 exactly.
    float* ws     = (float*)d_ws;
    float* dinv   = ws;                              // [0, 169344)
    int*   rowptr = (int*)(ws + 169344);             // NN+1 ints
    int*   pos    = (int*)(ws + 338688);             // NN ints (counts, then cursor)
    int*   bsum   = (int*)(ws + 508032);             // NB_SCAN ints (pad 512)
    int*   srcs   = (int*)(ws + 508544);             // NE ints (pad 1166336)
    float* wns    = ws + 1674880;                    // NE floats (pad 1166336)
    float* A      = ws + 2841216;                    // NN*FF
    float* B      = A + (size_t)NN * FF;             // NN*FF

    dim3 blk(256);
    const int gN  = cdiv(NN, 256);                   // 662
    const int gE  = cdiv(NE, 256);                   // 4556
    const int gW  = cdiv(NN, 4);                     // 42336 (4 waves/block)

    // ---- CSR build ----
    k_zeroi      <<<gN, blk, 0, stream>>>(pos, NN);
    k_hist       <<<gE, blk, 0, stream>>>(D, pos, NE);
    k_dinv       <<<gN, blk, 0, stream>>>(dinv, pos, NN);
    k_blksum     <<<NB_SCAN, blk, 0, stream>>>(pos, bsum);
    k_scan_root  <<<1, blk, 0, stream>>>(bsum, NB_SCAN);
    k_scan_final <<<NB_SCAN, blk, 0, stream>>>(pos, bsum, rowptr);
    k_fillpos    <<<gN, blk, 0, stream>>>(rowptr, pos, NN);
    k_scatter    <<<gE, blk, 0, stream>>>(S, D, dinv, pos, srcs, wns, NE);

    // ---- layer 1: A = x@W1 ; B = relu(Ahat*A + b1) ----
    k_gemm128 <<<cdiv(NN, 64), blk, 0, stream>>>(x, W1, A, NN);
    k_agg128<1> <<<gW, blk, 0, stream>>>(A, dinv, rowptr, srcs, wns, b1, B);

    // ---- layer 2: A = B@W2 ; B = Ahat*A + b2 ----
    k_gemm128 <<<cdiv(NN, 64), blk, 0, stream>>>(B, W2, A, NN);
    k_agg128<0> <<<gW, blk, 0, stream>>>(A, dinv, rowptr, srcs, wns, b2, B);

    // ---- layer 3: A[:,:40] = B@W3 ; out = log_softmax(Ahat*A + b3) ----
    k_gemm40 <<<cdiv(NN, 32), blk, 0, stream>>>(B, W3, A, NN);
    k_agg40lsm <<<gW, blk, 0, stream>>>(A, dinv, rowptr, srcs, wns, b3, out);
}

// Round 6
// 704.475 us; speedup vs baseline: 6.5686x; 1.2704x over previous
//
#include <hip/hip_runtime.h>
#include <math.h>

#define NN 169343
#define NE 1166243
#define FF 128
#define NC 40
#define NB_SCAN 166   // cdiv(NN, 1024)

static inline int cdiv(long long a, long long b){ return (int)((a + b - 1) / b); }

// bf16 helpers (RNE pack, shift unpack)
__device__ __forceinline__ unsigned short f2b(float f){
    unsigned u = __float_as_uint(f);
    return (unsigned short)((u + 0x7fffu + ((u >> 16) & 1u)) >> 16);
}
__device__ __forceinline__ float blo(unsigned v){ return __uint_as_float(v << 16); }
__device__ __forceinline__ float bhi(unsigned v){ return __uint_as_float(v & 0xffff0000u); }

// ================= CSR build =================

__global__ void k_zeroi(int* __restrict__ p, int n){
    int i = blockIdx.x * 256 + threadIdx.x;
    if (i < n) p[i] = 0;
}

__global__ void k_hist(const int* __restrict__ D, int* __restrict__ cnt, int E){
    int e = blockIdx.x * 256 + threadIdx.x;
    if (e < E) atomicAdd(&cnt[D[e]], 1);
}

__global__ void k_dinv(float* __restrict__ dinv, const int* __restrict__ cnt, int n){
    int i = blockIdx.x * 256 + threadIdx.x;
    if (i < n) dinv[i] = rsqrtf((float)(cnt[i] + 1));   // +1 self loop
}

__global__ __launch_bounds__(256) void k_blksum(const int* __restrict__ cnt, int* __restrict__ bsum){
    __shared__ int wsum[4];
    int t = threadIdx.x;
    int base = blockIdx.x * 1024 + t * 4;
    int s = 0;
#pragma unroll
    for (int j = 0; j < 4; j++) if (base + j < NN) s += cnt[base + j];
#pragma unroll
    for (int off = 32; off; off >>= 1) s += __shfl_down(s, off);
    if ((t & 63) == 0) wsum[t >> 6] = s;
    __syncthreads();
    if (t == 0) bsum[blockIdx.x] = wsum[0] + wsum[1] + wsum[2] + wsum[3];
}

__global__ __launch_bounds__(256) void k_scan_root(int* __restrict__ bsum, int nb){
    __shared__ int sh[256];
    int t = threadIdx.x;
    int v = (t < nb) ? bsum[t] : 0;
    sh[t] = v; __syncthreads();
    for (int d = 1; d < 256; d <<= 1){
        int add = (t >= d) ? sh[t - d] : 0;
        __syncthreads();
        sh[t] += add;
        __syncthreads();
    }
    if (t < nb) bsum[t] = sh[t] - v;   // exclusive
}

__global__ __launch_bounds__(256) void k_scan_final(const int* __restrict__ cnt,
                                                    const int* __restrict__ bsumEx,
                                                    int* __restrict__ rowptr){
    __shared__ int sh[256];
    int t = threadIdx.x;
    int base = blockIdx.x * 1024 + t * 4;
    int v0=0,v1=0,v2=0,v3=0;
    if (base + 0 < NN) v0 = cnt[base + 0];
    if (base + 1 < NN) v1 = cnt[base + 1];
    if (base + 2 < NN) v2 = cnt[base + 2];
    if (base + 3 < NN) v3 = cnt[base + 3];
    int tsum = v0 + v1 + v2 + v3;
    sh[t] = tsum; __syncthreads();
    for (int d = 1; d < 256; d <<= 1){
        int add = (t >= d) ? sh[t - d] : 0;
        __syncthreads();
        sh[t] += add;
        __syncthreads();
    }
    int off = sh[t] - tsum + bsumEx[blockIdx.x];
    if (base + 0 < NN) rowptr[base + 0] = off;
    if (base + 1 < NN) rowptr[base + 1] = off + v0;
    if (base + 2 < NN) rowptr[base + 2] = off + v0 + v1;
    if (base + 3 < NN) rowptr[base + 3] = off + v0 + v1 + v2;
}

__global__ void k_fillpos(const int* __restrict__ rowptr, int* __restrict__ pos, int n){
    int i = blockIdx.x * 256 + threadIdx.x;
    if (i < n) pos[i] = rowptr[i];
    if (i == 0) ((int*)rowptr)[NN] = NE;   // sentinel
}

__global__ void k_scatter(const int* __restrict__ S, const int* __restrict__ D,
                          const float* __restrict__ dinv, int* __restrict__ pos,
                          int* __restrict__ srcs, float* __restrict__ wns, int E){
    int e = blockIdx.x * 256 + threadIdx.x;
    if (e >= E) return;
    int s = S[e], d = D[e];
    int p = atomicAdd(&pos[d], 1);
    srcs[p] = s;
    wns[p] = dinv[s] * dinv[d];
}

// ================= GEMM 128x128: fp32 in, fp32 math, bf16 out =================

__global__ __launch_bounds__(256) void k_gemm128(const float* __restrict__ A,
                                                 const float* __restrict__ W,
                                                 unsigned short* __restrict__ Hb, int M){
    __shared__ float Ash[64][32];
    __shared__ float Wsh[32][128];
    const int tid = threadIdx.x;
    const int ct = tid & 31, rt = tid >> 5;
    const int c0 = ct * 4;
    const int row0 = blockIdx.x * 64;
    float acc[8][4] = {};
    for (int kc = 0; kc < 128; kc += 32){
        __syncthreads();
#pragma unroll
        for (int i = 0; i < 2; i++){
            int q = tid + 256 * i; int r = q >> 3; int c4 = (q & 7) * 4;
            int gr = row0 + r;
            float4 v = {0.f, 0.f, 0.f, 0.f};
            if (gr < M) v = *(const float4*)&A[(size_t)gr * FF + kc + c4];
            *(float4*)&Ash[r][c4] = v;
        }
#pragma unroll
        for (int i = 0; i < 4; i++){
            int q = tid + 256 * i; int r = q >> 5; int c4 = (q & 31) * 4;
            *(float4*)&Wsh[r][c4] = *(const float4*)&W[(size_t)(kc + r) * FF + c4];
        }
        __syncthreads();
#pragma unroll
        for (int k4 = 0; k4 < 32; k4 += 4){
            float4 w0 = *(const float4*)&Wsh[k4 + 0][c0];
            float4 w1 = *(const float4*)&Wsh[k4 + 1][c0];
            float4 w2 = *(const float4*)&Wsh[k4 + 2][c0];
            float4 w3 = *(const float4*)&Wsh[k4 + 3][c0];
#pragma unroll
            for (int i = 0; i < 8; i++){
                float4 a = *(const float4*)&Ash[rt * 8 + i][k4];
                acc[i][0] = fmaf(a.w,w3.x, fmaf(a.z,w2.x, fmaf(a.y,w1.x, fmaf(a.x,w0.x, acc[i][0]))));
                acc[i][1] = fmaf(a.w,w3.y, fmaf(a.z,w2.y, fmaf(a.y,w1.y, fmaf(a.x,w0.y, acc[i][1]))));
                acc[i][2] = fmaf(a.w,w3.z, fmaf(a.z,w2.z, fmaf(a.y,w1.z, fmaf(a.x,w0.z, acc[i][2]))));
                acc[i][3] = fmaf(a.w,w3.w, fmaf(a.z,w2.w, fmaf(a.y,w1.w, fmaf(a.x,w0.w, acc[i][3]))));
            }
        }
    }
#pragma unroll
    for (int i = 0; i < 8; i++){
        int gr = row0 + rt * 8 + i;
        if (gr < M){
            ushort4 h = {f2b(acc[i][0]), f2b(acc[i][1]), f2b(acc[i][2]), f2b(acc[i][3])};
            *(ushort4*)&Hb[(size_t)gr * FF + c0] = h;
        }
    }
}

// ================= GEMM 128x40 (fp32 out, final layer) =================

__global__ __launch_bounds__(256) void k_gemm40(const float* __restrict__ A,
                                                const float* __restrict__ W,
                                                float* __restrict__ out, int M){
    __shared__ float Wsh[128][40];
    __shared__ float Ash[32][132];
    const int tid = threadIdx.x;
    const int rt = tid >> 3, ct = tid & 7;
    const int cb = ct * 5;
    const int row0 = blockIdx.x * 32;
#pragma unroll
    for (int i = 0; i < 5; i++){
        int q = tid + 256 * i;
        int r = q / 10, c4 = (q % 10) * 4;
        *(float4*)&Wsh[r][c4] = *(const float4*)&W[(size_t)r * NC + c4];
    }
#pragma unroll
    for (int i = 0; i < 4; i++){
        int q = tid + 256 * i; int r = q >> 5, c4 = (q & 31) * 4;
        int gr = row0 + r;
        float4 v = {0.f, 0.f, 0.f, 0.f};
        if (gr < M) v = *(const float4*)&A[(size_t)gr * FF + c4];
        *(float4*)&Ash[r][c4] = v;
    }
    __syncthreads();
    float acc[5] = {};
    for (int k4 = 0; k4 < 128; k4 += 4){
        float4 a = *(const float4*)&Ash[rt][k4];
#pragma unroll
        for (int j = 0; j < 5; j++){
            acc[j] = fmaf(a.x, Wsh[k4 + 0][cb + j], acc[j]);
            acc[j] = fmaf(a.y, Wsh[k4 + 1][cb + j], acc[j]);
            acc[j] = fmaf(a.z, Wsh[k4 + 2][cb + j], acc[j]);
            acc[j] = fmaf(a.w, Wsh[k4 + 3][cb + j], acc[j]);
        }
    }
    int gr = row0 + rt;
    if (gr < M){
#pragma unroll
        for (int j = 0; j < 5; j++) out[(size_t)gr * NC + cb + j] = acc[j];
    }
}

// ================= CSR gather aggregation, bf16 operand, unroll x4 =================
// One wave per row; lane l owns cols [2l, 2l+1] (one uint = 2 bf16 per row-load).

template<int RELU>
__global__ __launch_bounds__(256) void k_agg128(const unsigned short* __restrict__ Hb,
                                                const float* __restrict__ dinv,
                                                const int* __restrict__ rowptr,
                                                const int* __restrict__ srcs,
                                                const float* __restrict__ wns,
                                                const float* __restrict__ bias,
                                                float* __restrict__ OUT){
    int wv = (blockIdx.x * 256 + threadIdx.x) >> 6;
    int lane = threadIdx.x & 63;
    if (wv >= NN) return;                             // wave-uniform exit
    int r0 = rowptr[wv], r1 = rowptr[wv + 1];
    float dv = dinv[wv];
    float sw = dv * dv;
    unsigned hv = ((const unsigned*)(Hb + (size_t)wv * FF))[lane];
    float ax = blo(hv) * sw, ay = bhi(hv) * sw;
    int e = r0;
    for (; e + 4 <= r1; e += 4){
        int s0 = srcs[e], s1 = srcs[e+1], s2 = srcs[e+2], s3 = srcs[e+3];
        float w0 = wns[e], w1 = wns[e+1], w2 = wns[e+2], w3 = wns[e+3];
        unsigned v0 = ((const unsigned*)(Hb + (size_t)s0 * FF))[lane];
        unsigned v1 = ((const unsigned*)(Hb + (size_t)s1 * FF))[lane];
        unsigned v2 = ((const unsigned*)(Hb + (size_t)s2 * FF))[lane];
        unsigned v3 = ((const unsigned*)(Hb + (size_t)s3 * FF))[lane];
        ax = fmaf(blo(v0), w0, ax); ay = fmaf(bhi(v0), w0, ay);
        ax = fmaf(blo(v1), w1, ax); ay = fmaf(bhi(v1), w1, ay);
        ax = fmaf(blo(v2), w2, ax); ay = fmaf(bhi(v2), w2, ay);
        ax = fmaf(blo(v3), w3, ax); ay = fmaf(bhi(v3), w3, ay);
    }
    for (; e < r1; ++e){
        int s = srcs[e];
        float wn = wns[e];
        unsigned v = ((const unsigned*)(Hb + (size_t)s * FF))[lane];
        ax = fmaf(blo(v), wn, ax); ay = fmaf(bhi(v), wn, ay);
    }
    float2 bb = *(const float2*)&bias[lane * 2];
    ax += bb.x; ay += bb.y;
    if (RELU){ ax = fmaxf(ax, 0.f); ay = fmaxf(ay, 0.f); }
    float2 o = {ax, ay};
    *(float2*)&OUT[(size_t)wv * FF + lane * 2] = o;
}

// 40-wide fp32 gather + bias + log_softmax, unroll x4. One wave per row.
__global__ __launch_bounds__(256) void k_agg40lsm(const float* __restrict__ H,
                                                  const float* __restrict__ dinv,
                                                  const int* __restrict__ rowptr,
                                                  const int* __restrict__ srcs,
                                                  const float* __restrict__ wns,
                                                  const float* __restrict__ bias,
                                                  float* __restrict__ OUT){
    int wv = (blockIdx.x * 256 + threadIdx.x) >> 6;
    int lane = threadIdx.x & 63;
    if (wv >= NN) return;
    int r0 = rowptr[wv], r1 = rowptr[wv + 1];
    float dv = dinv[wv];
    float acc = 0.f;
    if (lane < NC) acc = H[(size_t)wv * NC + lane] * dv * dv;
    int e = r0;
    for (; e + 4 <= r1; e += 4){
        int s0 = srcs[e], s1 = srcs[e+1], s2 = srcs[e+2], s3 = srcs[e+3];
        float w0 = wns[e], w1 = wns[e+1], w2 = wns[e+2], w3 = wns[e+3];
        if (lane < NC){
            float h0 = H[(size_t)s0 * NC + lane];
            float h1 = H[(size_t)s1 * NC + lane];
            float h2 = H[(size_t)s2 * NC + lane];
            float h3 = H[(size_t)s3 * NC + lane];
            acc = fmaf(h0, w0, acc);
            acc = fmaf(h1, w1, acc);
            acc = fmaf(h2, w2, acc);
            acc = fmaf(h3, w3, acc);
        }
    }
    for (; e < r1; ++e){
        int s = srcs[e];
        float wn = wns[e];
        if (lane < NC) acc = fmaf(H[(size_t)s * NC + lane], wn, acc);
    }
    float val = (lane < NC) ? acc + bias[lane] : -INFINITY;
    float m = val;
#pragma unroll
    for (int off = 32; off; off >>= 1) m = fmaxf(m, __shfl_xor(m, off));
    float ex = (lane < NC) ? expf(val - m) : 0.f;
    float sm = ex;
#pragma unroll
    for (int off = 32; off; off >>= 1) sm += __shfl_xor(sm, off);
    float ls = logf(sm);
    if (lane < NC) OUT[(size_t)wv * NC + lane] = val - m - ls;
}

// ================= launch =================

extern "C" void kernel_launch(void* const* d_in, const int* in_sizes, int n_in,
                              void* d_out, int out_size, void* d_ws, size_t ws_size,
                              hipStream_t stream){
    const float* x  = (const float*)d_in[0];
    const int*   ei = (const int*)d_in[1];
    const float* W1 = (const float*)d_in[2];
    const float* b1 = (const float*)d_in[3];
    const float* W2 = (const float*)d_in[4];
    const float* b2 = (const float*)d_in[5];
    const float* W3 = (const float*)d_in[6];
    const float* b3 = (const float*)d_in[7];
    const int* S = ei;
    const int* D = ei + NE;
    float* out = (float*)d_out;

    // workspace layout (units of 4B floats)
    float* ws     = (float*)d_ws;
    float* dinv   = ws;                              // [0, 169344)
    int*   rowptr = (int*)(ws + 169344);             // NN+1 ints
    int*   pos    = (int*)(ws + 338688);             // NN ints
    int*   bsum   = (int*)(ws + 508032);             // NB_SCAN ints (pad 512)
    int*   srcs   = (int*)(ws + 508544);             // NE ints (pad 1166336)
    float* wns    = ws + 1674880;                    // NE floats (pad 1166336)
    unsigned short* Hb = (unsigned short*)(ws + 2841216);  // NN*128 bf16 = 10837952 floats
    float* H3     = ws + 2841216;                    // NN*40 fp32 overlay (after Hb dead)
    float* B      = ws + 13679168;                   // NN*128 fp32
    // total: 13679168 + 21675904 = 35355072 floats = 141.4 MB

    dim3 blk(256);
    const int gN  = cdiv(NN, 256);
    const int gE  = cdiv(NE, 256);
    const int gW  = cdiv(NN, 4);                     // 4 waves/block

    // ---- CSR build ----
    k_zeroi      <<<gN, blk, 0, stream>>>(pos, NN);
    k_hist       <<<gE, blk, 0, stream>>>(D, pos, NE);
    k_dinv       <<<gN, blk, 0, stream>>>(dinv, pos, NN);
    k_blksum     <<<NB_SCAN, blk, 0, stream>>>(pos, bsum);
    k_scan_root  <<<1, blk, 0, stream>>>(bsum, NB_SCAN);
    k_scan_final <<<NB_SCAN, blk, 0, stream>>>(pos, bsum, rowptr);
    k_fillpos    <<<gN, blk, 0, stream>>>(rowptr, pos, NN);
    k_scatter    <<<gE, blk, 0, stream>>>(S, D, dinv, pos, srcs, wns, NE);

    // ---- layer 1: Hb = bf16(x@W1) ; B = relu(Ahat*Hb + b1) ----
    k_gemm128 <<<cdiv(NN, 64), blk, 0, stream>>>(x, W1, Hb, NN);
    k_agg128<1> <<<gW, blk, 0, stream>>>(Hb, dinv, rowptr, srcs, wns, b1, B);

    // ---- layer 2: Hb = bf16(B@W2) ; B = Ahat*Hb + b2 (in place over B) ----
    k_gemm128 <<<cdiv(NN, 64), blk, 0, stream>>>(B, W2, Hb, NN);
    k_agg128<0> <<<gW, blk, 0, stream>>>(Hb, dinv, rowptr, srcs, wns, b2, B);

    // ---- layer 3: H3 = B@W3 (fp32) ; out = log_softmax(Ahat*H3 + b3) ----
    k_gemm40 <<<cdiv(NN, 32), blk, 0, stream>>>(B, W3, H3, NN);
    k_agg40lsm <<<gW, blk, 0, stream>>>(H3, dinv, rowptr, srcs, wns, b3, out);
}

// Round 7
// 628.289 us; speedup vs baseline: 7.3651x; 1.1213x over previous
//
#include <hip/hip_runtime.h>
#include <math.h>

#define NN 169343
#define NE 1166243
#define FF 128
#define NC 40
#define NB_SCAN 166   // cdiv(NN, 1024)

static inline int cdiv(long long a, long long b){ return (int)((a + b - 1) / b); }

typedef __attribute__((ext_vector_type(8))) short short8;
typedef __attribute__((ext_vector_type(4))) float f32x4;

// bf16 helpers (RNE pack, shift unpack)
__device__ __forceinline__ unsigned short f2b(float f){
    unsigned u = __float_as_uint(f);
    return (unsigned short)((u + 0x7fffu + ((u >> 16) & 1u)) >> 16);
}
__device__ __forceinline__ float blo(unsigned v){ return __uint_as_float(v << 16); }
__device__ __forceinline__ float bhi(unsigned v){ return __uint_as_float(v & 0xffff0000u); }

// ================= CSR build =================

__global__ void k_zeroi(int* __restrict__ p, int n){
    int i = blockIdx.x * 256 + threadIdx.x;
    if (i < n) p[i] = 0;
}

__global__ void k_hist(const int* __restrict__ D, int* __restrict__ cnt, int E){
    int e = blockIdx.x * 256 + threadIdx.x;
    if (e < E) atomicAdd(&cnt[D[e]], 1);
}

__global__ void k_dinv(float* __restrict__ dinv, const int* __restrict__ cnt, int n){
    int i = blockIdx.x * 256 + threadIdx.x;
    if (i < n) dinv[i] = rsqrtf((float)(cnt[i] + 1));   // +1 self loop
}

__global__ __launch_bounds__(256) void k_blksum(const int* __restrict__ cnt, int* __restrict__ bsum){
    __shared__ int wsum[4];
    int t = threadIdx.x;
    int base = blockIdx.x * 1024 + t * 4;
    int s = 0;
#pragma unroll
    for (int j = 0; j < 4; j++) if (base + j < NN) s += cnt[base + j];
#pragma unroll
    for (int off = 32; off; off >>= 1) s += __shfl_down(s, off);
    if ((t & 63) == 0) wsum[t >> 6] = s;
    __syncthreads();
    if (t == 0) bsum[blockIdx.x] = wsum[0] + wsum[1] + wsum[2] + wsum[3];
}

__global__ __launch_bounds__(256) void k_scan_root(int* __restrict__ bsum, int nb){
    __shared__ int sh[256];
    int t = threadIdx.x;
    int v = (t < nb) ? bsum[t] : 0;
    sh[t] = v; __syncthreads();
    for (int d = 1; d < 256; d <<= 1){
        int add = (t >= d) ? sh[t - d] : 0;
        __syncthreads();
        sh[t] += add;
        __syncthreads();
    }
    if (t < nb) bsum[t] = sh[t] - v;   // exclusive
}

__global__ __launch_bounds__(256) void k_scan_final(const int* __restrict__ cnt,
                                                    const int* __restrict__ bsumEx,
                                                    int* __restrict__ rowptr){
    __shared__ int sh[256];
    int t = threadIdx.x;
    int base = blockIdx.x * 1024 + t * 4;
    int v0=0,v1=0,v2=0,v3=0;
    if (base + 0 < NN) v0 = cnt[base + 0];
    if (base + 1 < NN) v1 = cnt[base + 1];
    if (base + 2 < NN) v2 = cnt[base + 2];
    if (base + 3 < NN) v3 = cnt[base + 3];
    int tsum = v0 + v1 + v2 + v3;
    sh[t] = tsum; __syncthreads();
    for (int d = 1; d < 256; d <<= 1){
        int add = (t >= d) ? sh[t - d] : 0;
        __syncthreads();
        sh[t] += add;
        __syncthreads();
    }
    int off = sh[t] - tsum + bsumEx[blockIdx.x];
    if (base + 0 < NN) rowptr[base + 0] = off;
    if (base + 1 < NN) rowptr[base + 1] = off + v0;
    if (base + 2 < NN) rowptr[base + 2] = off + v0 + v1;
    if (base + 3 < NN) rowptr[base + 3] = off + v0 + v1 + v2;
}

__global__ void k_fillpos(const int* __restrict__ rowptr, int* __restrict__ pos, int n){
    int i = blockIdx.x * 256 + threadIdx.x;
    if (i < n) pos[i] = rowptr[i];
    if (i == 0) ((int*)rowptr)[NN] = NE;   // sentinel
}

__global__ void k_scatter(const int* __restrict__ S, const int* __restrict__ D,
                          const float* __restrict__ dinv, int* __restrict__ pos,
                          int* __restrict__ srcs, float* __restrict__ wns, int E){
    int e = blockIdx.x * 256 + threadIdx.x;
    if (e >= E) return;
    int s = S[e], d = D[e];
    int p = atomicAdd(&pos[d], 1);
    srcs[p] = s;
    wns[p] = dinv[s] * dinv[d];
}

// W[k][n] fp32 -> Wt[n][k] bf16 (transpose + quantize), 128x128
__global__ void k_cvtW(const float* __restrict__ W, unsigned short* __restrict__ Wt){
    int i = blockIdx.x * 256 + threadIdx.x;     // 16384
    int c = i >> 7, k = i & 127;
    Wt[c * FF + k] = f2b(W[k * FF + c]);
}

// ================= MFMA GEMM: H[M][128] = A[M][128] @ W, bf16 in, fp32 acc, bf16 out ====
// LDS-free. Wave owns 16 rows x 128 cols. A-frag: lane = (row l&15, k-group (l>>4)*8).
// B-frag from Wt[n][k] (L1-resident 32 KB). C/D: col=lane&15, row=(lane>>4)*4+reg.

template<int AFP32>
__global__ __launch_bounds__(256) void k_gemm128m(const void* __restrict__ Ap,
                                                  const unsigned short* __restrict__ Wt,
                                                  unsigned short* __restrict__ Hb, int M){
    const int lane = threadIdx.x & 63;
    const int wid = threadIdx.x >> 6;
    const int m0 = (blockIdx.x * 4 + wid) * 16;
    const int row = m0 + (lane & 15);
    const int kg = (lane >> 4) * 8;
    const bool rowok = row < M;
    f32x4 acc[8] = {};
#pragma unroll
    for (int kk = 0; kk < 4; kk++){
        const int k0 = kk * 32 + kg;
        short8 a = {0,0,0,0,0,0,0,0};
        if (rowok){
            if (AFP32){
                const float* A = (const float*)Ap;
                const float* p = &A[(size_t)row * FF + k0];
                float4 u0 = *(const float4*)p;
                float4 u1 = *(const float4*)(p + 4);
                a[0]=(short)f2b(u0.x); a[1]=(short)f2b(u0.y); a[2]=(short)f2b(u0.z); a[3]=(short)f2b(u0.w);
                a[4]=(short)f2b(u1.x); a[5]=(short)f2b(u1.y); a[6]=(short)f2b(u1.z); a[7]=(short)f2b(u1.w);
            } else {
                const unsigned short* Ab = (const unsigned short*)Ap;
                a = *(const short8*)&Ab[(size_t)row * FF + k0];
            }
        }
#pragma unroll
        for (int n = 0; n < 8; n++){
            short8 b = *(const short8*)&Wt[(size_t)(n * 16 + (lane & 15)) * FF + k0];
            acc[n] = __builtin_amdgcn_mfma_f32_16x16x32_bf16(a, b, acc[n], 0, 0, 0);
        }
    }
    const int orow0 = m0 + (lane >> 4) * 4;
    const int ocol = lane & 15;
#pragma unroll
    for (int n = 0; n < 8; n++){
#pragma unroll
        for (int r = 0; r < 4; r++){
            int orow = orow0 + r;
            if (orow < M) Hb[(size_t)orow * FF + n * 16 + ocol] = f2b(acc[n][r]);
        }
    }
}

// ================= GEMM 128x40 fp32 (final layer) =================

__global__ __launch_bounds__(256) void k_gemm40(const float* __restrict__ A,
                                                const float* __restrict__ W,
                                                float* __restrict__ out, int M){
    __shared__ float Wsh[128][40];
    __shared__ float Ash[32][132];
    const int tid = threadIdx.x;
    const int rt = tid >> 3, ct = tid & 7;
    const int cb = ct * 5;
    const int row0 = blockIdx.x * 32;
#pragma unroll
    for (int i = 0; i < 5; i++){
        int q = tid + 256 * i;
        int r = q / 10, c4 = (q % 10) * 4;
        *(float4*)&Wsh[r][c4] = *(const float4*)&W[(size_t)r * NC + c4];
    }
#pragma unroll
    for (int i = 0; i < 4; i++){
        int q = tid + 256 * i; int r = q >> 5, c4 = (q & 31) * 4;
        int gr = row0 + r;
        float4 v = {0.f, 0.f, 0.f, 0.f};
        if (gr < M) v = *(const float4*)&A[(size_t)gr * FF + c4];
        *(float4*)&Ash[r][c4] = v;
    }
    __syncthreads();
    float acc[5] = {};
    for (int k4 = 0; k4 < 128; k4 += 4){
        float4 a = *(const float4*)&Ash[rt][k4];
#pragma unroll
        for (int j = 0; j < 5; j++){
            acc[j] = fmaf(a.x, Wsh[k4 + 0][cb + j], acc[j]);
            acc[j] = fmaf(a.y, Wsh[k4 + 1][cb + j], acc[j]);
            acc[j] = fmaf(a.z, Wsh[k4 + 2][cb + j], acc[j]);
            acc[j] = fmaf(a.w, Wsh[k4 + 3][cb + j], acc[j]);
        }
    }
    int gr = row0 + rt;
    if (gr < M){
#pragma unroll
        for (int j = 0; j < 5; j++) out[(size_t)gr * NC + cb + j] = acc[j];
    }
}

// ================= CSR gather, bf16 operand, index-prefetch + x8 MLP =================
// One wave per row; lane owns cols [2l,2l+1]. Indices/weights prefetched lane-parallel;
// OOB group lanes carry weight 0 (gather row 0 harmlessly).

template<int RELU, int OUTBF16>
__global__ __launch_bounds__(256) void k_agg128(const unsigned short* __restrict__ Hb,
                                                const float* __restrict__ dinv,
                                                const int* __restrict__ rowptr,
                                                const int* __restrict__ srcs,
                                                const float* __restrict__ wns,
                                                const float* __restrict__ bias,
                                                void* __restrict__ OUTp){
    int wv = (blockIdx.x * 256 + threadIdx.x) >> 6;
    int lane = threadIdx.x & 63;
    if (wv >= NN) return;                             // wave-uniform exit
    int r0 = rowptr[wv], r1 = rowptr[wv + 1];
    float dv = dinv[wv];
    float sw = dv * dv;
    unsigned hv = ((const unsigned*)(Hb + (size_t)wv * FF))[lane];
    float ax = blo(hv) * sw, ay = bhi(hv) * sw;
    for (int base = r0; base < r1; base += 64){
        int len = r1 - base; if (len > 64) len = 64;
        int   sv = (lane < len) ? srcs[base + lane] : 0;
        float wl = (lane < len) ? wns[base + lane] : 0.f;
        for (int j = 0; j < len; j += 8){
            int s0=__shfl(sv,j+0), s1=__shfl(sv,j+1), s2=__shfl(sv,j+2), s3=__shfl(sv,j+3);
            int s4=__shfl(sv,j+4), s5=__shfl(sv,j+5), s6=__shfl(sv,j+6), s7=__shfl(sv,j+7);
            float w0=__shfl(wl,j+0), w1=__shfl(wl,j+1), w2=__shfl(wl,j+2), w3=__shfl(wl,j+3);
            float w4=__shfl(wl,j+4), w5=__shfl(wl,j+5), w6=__shfl(wl,j+6), w7=__shfl(wl,j+7);
            unsigned v0 = ((const unsigned*)(Hb + (size_t)s0 * FF))[lane];
            unsigned v1 = ((const unsigned*)(Hb + (size_t)s1 * FF))[lane];
            unsigned v2 = ((const unsigned*)(Hb + (size_t)s2 * FF))[lane];
            unsigned v3 = ((const unsigned*)(Hb + (size_t)s3 * FF))[lane];
            unsigned v4 = ((const unsigned*)(Hb + (size_t)s4 * FF))[lane];
            unsigned v5 = ((const unsigned*)(Hb + (size_t)s5 * FF))[lane];
            unsigned v6 = ((const unsigned*)(Hb + (size_t)s6 * FF))[lane];
            unsigned v7 = ((const unsigned*)(Hb + (size_t)s7 * FF))[lane];
            ax = fmaf(blo(v0), w0, ax); ay = fmaf(bhi(v0), w0, ay);
            ax = fmaf(blo(v1), w1, ax); ay = fmaf(bhi(v1), w1, ay);
            ax = fmaf(blo(v2), w2, ax); ay = fmaf(bhi(v2), w2, ay);
            ax = fmaf(blo(v3), w3, ax); ay = fmaf(bhi(v3), w3, ay);
            ax = fmaf(blo(v4), w4, ax); ay = fmaf(bhi(v4), w4, ay);
            ax = fmaf(blo(v5), w5, ax); ay = fmaf(bhi(v5), w5, ay);
            ax = fmaf(blo(v6), w6, ax); ay = fmaf(bhi(v6), w6, ay);
            ax = fmaf(blo(v7), w7, ax); ay = fmaf(bhi(v7), w7, ay);
        }
    }
    float2 bb = *(const float2*)&bias[lane * 2];
    ax += bb.x; ay += bb.y;
    if (RELU){ ax = fmaxf(ax, 0.f); ay = fmaxf(ay, 0.f); }
    if (OUTBF16){
        unsigned o = (unsigned)f2b(ax) | ((unsigned)f2b(ay) << 16);
        ((unsigned*)OUTp)[(size_t)wv * 64 + lane] = o;
    } else {
        float2 o = {ax, ay};
        *(float2*)&((float*)OUTp)[(size_t)wv * FF + lane * 2] = o;
    }
}

// 40-wide fp32 gather + bias + log_softmax, index-prefetch + x8. One wave per row.
__global__ __launch_bounds__(256) void k_agg40lsm(const float* __restrict__ H,
                                                  const float* __restrict__ dinv,
                                                  const int* __restrict__ rowptr,
                                                  const int* __restrict__ srcs,
                                                  const float* __restrict__ wns,
                                                  const float* __restrict__ bias,
                                                  float* __restrict__ OUT){
    int wv = (blockIdx.x * 256 + threadIdx.x) >> 6;
    int lane = threadIdx.x & 63;
    if (wv >= NN) return;
    int r0 = rowptr[wv], r1 = rowptr[wv + 1];
    float dv = dinv[wv];
    float acc = 0.f;
    if (lane < NC) acc = H[(size_t)wv * NC + lane] * dv * dv;
    for (int base = r0; base < r1; base += 64){
        int len = r1 - base; if (len > 64) len = 64;
        int   sv = (lane < len) ? srcs[base + lane] : 0;
        float wl = (lane < len) ? wns[base + lane] : 0.f;
        for (int j = 0; j < len; j += 8){
            int s0=__shfl(sv,j+0), s1=__shfl(sv,j+1), s2=__shfl(sv,j+2), s3=__shfl(sv,j+3);
            int s4=__shfl(sv,j+4), s5=__shfl(sv,j+5), s6=__shfl(sv,j+6), s7=__shfl(sv,j+7);
            float w0=__shfl(wl,j+0), w1=__shfl(wl,j+1), w2=__shfl(wl,j+2), w3=__shfl(wl,j+3);
            float w4=__shfl(wl,j+4), w5=__shfl(wl,j+5), w6=__shfl(wl,j+6), w7=__shfl(wl,j+7);
            if (lane < NC){
                float h0 = H[(size_t)s0 * NC + lane];
                float h1 = H[(size_t)s1 * NC + lane];
                float h2 = H[(size_t)s2 * NC + lane];
                float h3 = H[(size_t)s3 * NC + lane];
                float h4 = H[(size_t)s4 * NC + lane];
                float h5 = H[(size_t)s5 * NC + lane];
                float h6 = H[(size_t)s6 * NC + lane];
                float h7 = H[(size_t)s7 * NC + lane];
                acc = fmaf(h0, w0, acc); acc = fmaf(h1, w1, acc);
                acc = fmaf(h2, w2, acc); acc = fmaf(h3, w3, acc);
                acc = fmaf(h4, w4, acc); acc = fmaf(h5, w5, acc);
                acc = fmaf(h6, w6, acc); acc = fmaf(h7, w7, acc);
            }
        }
    }
    float val = (lane < NC) ? acc + bias[lane] : -INFINITY;
    float m = val;
#pragma unroll
    for (int off = 32; off; off >>= 1) m = fmaxf(m, __shfl_xor(m, off));
    float ex = (lane < NC) ? expf(val - m) : 0.f;
    float sm = ex;
#pragma unroll
    for (int off = 32; off; off >>= 1) sm += __shfl_xor(sm, off);
    float ls = logf(sm);
    if (lane < NC) OUT[(size_t)wv * NC + lane] = val - m - ls;
}

// ================= launch =================

extern "C" void kernel_launch(void* const* d_in, const int* in_sizes, int n_in,
                              void* d_out, int out_size, void* d_ws, size_t ws_size,
                              hipStream_t stream){
    const float* x  = (const float*)d_in[0];
    const int*   ei = (const int*)d_in[1];
    const float* W1 = (const float*)d_in[2];
    const float* b1 = (const float*)d_in[3];
    const float* W2 = (const float*)d_in[4];
    const float* b2 = (const float*)d_in[5];
    const float* W3 = (const float*)d_in[6];
    const float* b3 = (const float*)d_in[7];
    const int* S = ei;
    const int* D = ei + NE;
    float* out = (float*)d_out;

    // workspace layout (units of 4B floats); peak 35.4M floats = 141.5 MB
    float* ws     = (float*)d_ws;
    float* dinv   = ws;                                       // NN
    int*   rowptr = (int*)(ws + 169344);                      // NN+1
    int*   pos    = (int*)(ws + 338688);                      // NN
    int*   bsum   = (int*)(ws + 508032);                      // pad 512
    int*   srcs   = (int*)(ws + 508544);                      // NE (pad 1166336)
    float* wns    = ws + 1674880;                             // NE (pad 1166336)
    unsigned short* Wt1 = (unsigned short*)(ws + 2841216);    // 128*128 bf16 = 8192 f
    unsigned short* Wt2 = (unsigned short*)(ws + 2849408);    // 8192 f
    unsigned short* Hb  = (unsigned short*)(ws + 2857600);    // NN*128 bf16 = 10837952 f
    float* H3     = ws + 2857600;                             // NN*40 fp32 overlay (Hb dead)
    unsigned short* B1b = (unsigned short*)(ws + 13695552);   // NN*128 bf16
    float* B2     = ws + 13695552;                            // NN*128 fp32 overlay (B1b dead)
    // B2 end: 13695552 + 21675904 = 35371456 floats

    dim3 blk(256);
    const int gN  = cdiv(NN, 256);
    const int gE  = cdiv(NE, 256);
    const int gW  = cdiv(NN, 4);                              // 4 waves/block
    const int gM  = cdiv(NN, 64);                             // MFMA gemm blocks

    // ---- CSR build + weight conversion ----
    k_zeroi      <<<gN, blk, 0, stream>>>(pos, NN);
    k_hist       <<<gE, blk, 0, stream>>>(D, pos, NE);
    k_dinv       <<<gN, blk, 0, stream>>>(dinv, pos, NN);
    k_blksum     <<<NB_SCAN, blk, 0, stream>>>(pos, bsum);
    k_scan_root  <<<1, blk, 0, stream>>>(bsum, NB_SCAN);
    k_scan_final <<<NB_SCAN, blk, 0, stream>>>(pos, bsum, rowptr);
    k_fillpos    <<<gN, blk, 0, stream>>>(rowptr, pos, NN);
    k_scatter    <<<gE, blk, 0, stream>>>(S, D, dinv, pos, srcs, wns, NE);
    k_cvtW       <<<64, blk, 0, stream>>>(W1, Wt1);
    k_cvtW       <<<64, blk, 0, stream>>>(W2, Wt2);

    // ---- layer 1: Hb = bf16(x@W1) ; B1b = bf16(relu(Ahat*Hb + b1)) ----
    k_gemm128m<1> <<<gM, blk, 0, stream>>>(x, Wt1, Hb, NN);
    k_agg128<1,1> <<<gW, blk, 0, stream>>>(Hb, dinv, rowptr, srcs, wns, b1, B1b);

    // ---- layer 2: Hb = bf16(B1b@W2) ; B2 = fp32(Ahat*Hb + b2) ----
    k_gemm128m<0> <<<gM, blk, 0, stream>>>(B1b, Wt2, Hb, NN);
    k_agg128<0,0> <<<gW, blk, 0, stream>>>(Hb, dinv, rowptr, srcs, wns, b2, B2);

    // ---- layer 3: H3 = B2@W3 (fp32) ; out = log_softmax(Ahat*H3 + b3) ----
    k_gemm40 <<<cdiv(NN, 32), blk, 0, stream>>>(B2, W3, H3, NN);
    k_agg40lsm <<<gW, blk, 0, stream>>>(H3, dinv, rowptr, srcs, wns, b3, out);
}

// Round 9
// 620.310 us; speedup vs baseline: 7.4599x; 1.0129x over previous
//
#include <hip/hip_runtime.h>
#include <math.h>

#define NN 169343
#define NE 1166243
#define FF 128
#define NC 40
#define NB_SCAN 166   // cdiv(NN, 1024)

static inline int cdiv(long long a, long long b){ return (int)((a + b - 1) / b); }

typedef __attribute__((ext_vector_type(8))) short short8;
typedef __attribute__((ext_vector_type(4))) float f32x4;

// bf16 helpers (RNE pack, shift unpack)
__device__ __forceinline__ unsigned short f2b(float f){
    unsigned u = __float_as_uint(f);
    return (unsigned short)((u + 0x7fffu + ((u >> 16) & 1u)) >> 16);
}
__device__ __forceinline__ float blo(unsigned v){ return __uint_as_float(v << 16); }
__device__ __forceinline__ float bhi(unsigned v){ return __uint_as_float(v & 0xffff0000u); }
__device__ __forceinline__ float b2f(unsigned short v){ return __uint_as_float((unsigned)v << 16); }

// ================= CSR build =================

__global__ void k_zeroi(int* __restrict__ p, int n){
    int i = blockIdx.x * 256 + threadIdx.x;
    if (i < n) p[i] = 0;
}

// 4 strided edges per thread: independent atomic chains, coalesced reads
__global__ void k_hist(const int* __restrict__ D, int* __restrict__ cnt, int E){
    int base = blockIdx.x * 1024 + threadIdx.x;
#pragma unroll
    for (int j = 0; j < 4; j++){
        int e = base + j * 256;
        if (e < E) atomicAdd(&cnt[D[e]], 1);
    }
}

__global__ void k_dinv(float* __restrict__ dinv, const int* __restrict__ cnt, int n){
    int i = blockIdx.x * 256 + threadIdx.x;
    if (i < n) dinv[i] = rsqrtf((float)(cnt[i] + 1));   // +1 self loop
}

__global__ __launch_bounds__(256) void k_blksum(const int* __restrict__ cnt, int* __restrict__ bsum){
    __shared__ int wsum[4];
    int t = threadIdx.x;
    int base = blockIdx.x * 1024 + t * 4;
    int s = 0;
#pragma unroll
    for (int j = 0; j < 4; j++) if (base + j < NN) s += cnt[base + j];
#pragma unroll
    for (int off = 32; off; off >>= 1) s += __shfl_down(s, off);
    if ((t & 63) == 0) wsum[t >> 6] = s;
    __syncthreads();
    if (t == 0) bsum[blockIdx.x] = wsum[0] + wsum[1] + wsum[2] + wsum[3];
}

__global__ __launch_bounds__(256) void k_scan_root(int* __restrict__ bsum, int nb){
    __shared__ int sh[256];
    int t = threadIdx.x;
    int v = (t < nb) ? bsum[t] : 0;
    sh[t] = v; __syncthreads();
    for (int d = 1; d < 256; d <<= 1){
        int add = (t >= d) ? sh[t - d] : 0;
        __syncthreads();
        sh[t] += add;
        __syncthreads();
    }
    if (t < nb) bsum[t] = sh[t] - v;   // exclusive
}

__global__ __launch_bounds__(256) void k_scan_final(const int* __restrict__ cnt,
                                                    const int* __restrict__ bsumEx,
                                                    int* __restrict__ rowptr){
    __shared__ int sh[256];
    int t = threadIdx.x;
    int base = blockIdx.x * 1024 + t * 4;
    int v0=0,v1=0,v2=0,v3=0;
    if (base + 0 < NN) v0 = cnt[base + 0];
    if (base + 1 < NN) v1 = cnt[base + 1];
    if (base + 2 < NN) v2 = cnt[base + 2];
    if (base + 3 < NN) v3 = cnt[base + 3];
    int tsum = v0 + v1 + v2 + v3;
    sh[t] = tsum; __syncthreads();
    for (int d = 1; d < 256; d <<= 1){
        int add = (t >= d) ? sh[t - d] : 0;
        __syncthreads();
        sh[t] += add;
        __syncthreads();
    }
    int off = sh[t] - tsum + bsumEx[blockIdx.x];
    if (base + 0 < NN) rowptr[base + 0] = off;
    if (base + 1 < NN) rowptr[base + 1] = off + v0;
    if (base + 2 < NN) rowptr[base + 2] = off + v0 + v1;
    if (base + 3 < NN) rowptr[base + 3] = off + v0 + v1 + v2;
}

__global__ void k_fillpos(const int* __restrict__ rowptr, int* __restrict__ pos, int n){
    int i = blockIdx.x * 256 + threadIdx.x;
    if (i < n) pos[i] = rowptr[i];
    if (i == 0) ((int*)rowptr)[NN] = NE;   // sentinel
}

// packed (src, wn) single 8B scattered store; 4 strided edges/thread
__global__ void k_scatter(const int* __restrict__ S, const int* __restrict__ D,
                          const float* __restrict__ dinv, int* __restrict__ pos,
                          int2* __restrict__ ew, int E){
    int base = blockIdx.x * 1024 + threadIdx.x;
#pragma unroll
    for (int j = 0; j < 4; j++){
        int e = base + j * 256;
        if (e < E){
            int s = S[e], d = D[e];
            float wn = dinv[s] * dinv[d];
            int p = atomicAdd(&pos[d], 1);
            ew[p] = make_int2(s, __float_as_int(wn));
        }
    }
}

// W[k][n] fp32 -> Wt[n][k] bf16 (transpose + quantize), 128x128
__global__ void k_cvtW(const float* __restrict__ W, unsigned short* __restrict__ Wt){
    int i = blockIdx.x * 256 + threadIdx.x;     // 16384
    int c = i >> 7, k = i & 127;
    Wt[c * FF + k] = f2b(W[k * FF + c]);
}

// ================= MFMA GEMM: H[M][128] = A[M][128] @ W, bf16 in, fp32 acc, bf16 out ====
// LDS-free. Wave owns 16 rows x 128 cols. A-frag: lane = (row l&15, k-group (l>>4)*8).
// B-frag from Wt[n][k] (L1-resident 32 KB). C/D: col=lane&15, row=(lane>>4)*4+reg.

template<int AFP32>
__global__ __launch_bounds__(256) void k_gemm128m(const void* __restrict__ Ap,
                                                  const unsigned short* __restrict__ Wt,
                                                  unsigned short* __restrict__ Hb, int M){
    const int lane = threadIdx.x & 63;
    const int wid = threadIdx.x >> 6;
    const int m0 = (blockIdx.x * 4 + wid) * 16;
    const int row = m0 + (lane & 15);
    const int kg = (lane >> 4) * 8;
    const bool rowok = row < M;
    f32x4 acc[8] = {};
#pragma unroll
    for (int kk = 0; kk < 4; kk++){
        const int k0 = kk * 32 + kg;
        short8 a = {0,0,0,0,0,0,0,0};
        if (rowok){
            if (AFP32){
                const float* A = (const float*)Ap;
                const float* p = &A[(size_t)row * FF + k0];
                float4 u0 = *(const float4*)p;
                float4 u1 = *(const float4*)(p + 4);
                a[0]=(short)f2b(u0.x); a[1]=(short)f2b(u0.y); a[2]=(short)f2b(u0.z); a[3]=(short)f2b(u0.w);
                a[4]=(short)f2b(u1.x); a[5]=(short)f2b(u1.y); a[6]=(short)f2b(u1.z); a[7]=(short)f2b(u1.w);
            } else {
                const unsigned short* Ab = (const unsigned short*)Ap;
                a = *(const short8*)&Ab[(size_t)row * FF + k0];
            }
        }
#pragma unroll
        for (int n = 0; n < 8; n++){
            short8 b = *(const short8*)&Wt[(size_t)(n * 16 + (lane & 15)) * FF + k0];
            acc[n] = __builtin_amdgcn_mfma_f32_16x16x32_bf16(a, b, acc[n], 0, 0, 0);
        }
    }
    const int orow0 = m0 + (lane >> 4) * 4;
    const int ocol = lane & 15;
#pragma unroll
    for (int n = 0; n < 8; n++){
#pragma unroll
        for (int r = 0; r < 4; r++){
            int orow = orow0 + r;
            if (orow < M) Hb[(size_t)orow * FF + n * 16 + ocol] = f2b(acc[n][r]);
        }
    }
}

// ================= GEMM 128x40: bf16 A, fp32 W/math, bf16 out =================

__global__ __launch_bounds__(256) void k_gemm40(const unsigned short* __restrict__ Ab,
                                                const float* __restrict__ W,
                                                unsigned short* __restrict__ H40, int M){
    __shared__ float Wsh[128][40];
    __shared__ float Ash[32][132];
    const int tid = threadIdx.x;
    const int rt = tid >> 3, ct = tid & 7;
    const int cb = ct * 5;
    const int row0 = blockIdx.x * 32;
#pragma unroll
    for (int i = 0; i < 5; i++){
        int q = tid + 256 * i;
        int r = q / 10, c4 = (q % 10) * 4;
        *(float4*)&Wsh[r][c4] = *(const float4*)&W[(size_t)r * NC + c4];
    }
#pragma unroll
    for (int i = 0; i < 4; i++){
        int q = tid + 256 * i; int r = q >> 5, c4 = (q & 31) * 4;
        int gr = row0 + r;
        ushort4 u = {0, 0, 0, 0};
        if (gr < M) u = *(const ushort4*)&Ab[(size_t)gr * FF + c4];
        Ash[r][c4 + 0] = b2f(u.x);
        Ash[r][c4 + 1] = b2f(u.y);
        Ash[r][c4 + 2] = b2f(u.z);
        Ash[r][c4 + 3] = b2f(u.w);
    }
    __syncthreads();
    float acc[5] = {};
    for (int k4 = 0; k4 < 128; k4 += 4){
        float4 a = *(const float4*)&Ash[rt][k4];
#pragma unroll
        for (int j = 0; j < 5; j++){
            acc[j] = fmaf(a.x, Wsh[k4 + 0][cb + j], acc[j]);
            acc[j] = fmaf(a.y, Wsh[k4 + 1][cb + j], acc[j]);
            acc[j] = fmaf(a.z, Wsh[k4 + 2][cb + j], acc[j]);
            acc[j] = fmaf(a.w, Wsh[k4 + 3][cb + j], acc[j]);
        }
    }
    int gr = row0 + rt;
    if (gr < M){
#pragma unroll
        for (int j = 0; j < 5; j++) H40[(size_t)gr * NC + cb + j] = f2b(acc[j]);
    }
}

// ================= CSR gather, bf16 operand, packed-edge prefetch + x8 MLP =================

template<int RELU, int OUTBF16>
__global__ __launch_bounds__(256) void k_agg128(const unsigned short* __restrict__ Hb,
                                                const float* __restrict__ dinv,
                                                const int* __restrict__ rowptr,
                                                const int2* __restrict__ ew,
                                                const float* __restrict__ bias,
                                                void* __restrict__ OUTp){
    int wv = (blockIdx.x * 256 + threadIdx.x) >> 6;
    int lane = threadIdx.x & 63;
    if (wv >= NN) return;                             // wave-uniform exit
    int r0 = rowptr[wv], r1 = rowptr[wv + 1];
    float dv = dinv[wv];
    float sw = dv * dv;
    unsigned hv = ((const unsigned*)(Hb + (size_t)wv * FF))[lane];
    float ax = blo(hv) * sw, ay = bhi(hv) * sw;
    for (int base = r0; base < r1; base += 64){
        int len = r1 - base; if (len > 64) len = 64;
        int2 ev = make_int2(0, 0);
        if (lane < len) ev = ew[base + lane];
        int sv = ev.x; float wl = __int_as_float(ev.y);
        for (int j = 0; j < len; j += 8){
            int s0=__shfl(sv,j+0), s1=__shfl(sv,j+1), s2=__shfl(sv,j+2), s3=__shfl(sv,j+3);
            int s4=__shfl(sv,j+4), s5=__shfl(sv,j+5), s6=__shfl(sv,j+6), s7=__shfl(sv,j+7);
            float w0=__shfl(wl,j+0), w1=__shfl(wl,j+1), w2=__shfl(wl,j+2), w3=__shfl(wl,j+3);
            float w4=__shfl(wl,j+4), w5=__shfl(wl,j+5), w6=__shfl(wl,j+6), w7=__shfl(wl,j+7);
            unsigned v0 = ((const unsigned*)(Hb + (size_t)s0 * FF))[lane];
            unsigned v1 = ((const unsigned*)(Hb + (size_t)s1 * FF))[lane];
            unsigned v2 = ((const unsigned*)(Hb + (size_t)s2 * FF))[lane];
            unsigned v3 = ((const unsigned*)(Hb + (size_t)s3 * FF))[lane];
            unsigned v4 = ((const unsigned*)(Hb + (size_t)s4 * FF))[lane];
            unsigned v5 = ((const unsigned*)(Hb + (size_t)s5 * FF))[lane];
            unsigned v6 = ((const unsigned*)(Hb + (size_t)s6 * FF))[lane];
            unsigned v7 = ((const unsigned*)(Hb + (size_t)s7 * FF))[lane];
            ax = fmaf(blo(v0), w0, ax); ay = fmaf(bhi(v0), w0, ay);
            ax = fmaf(blo(v1), w1, ax); ay = fmaf(bhi(v1), w1, ay);
            ax = fmaf(blo(v2), w2, ax); ay = fmaf(bhi(v2), w2, ay);
            ax = fmaf(blo(v3), w3, ax); ay = fmaf(bhi(v3), w3, ay);
            ax = fmaf(blo(v4), w4, ax); ay = fmaf(bhi(v4), w4, ay);
            ax = fmaf(blo(v5), w5, ax); ay = fmaf(bhi(v5), w5, ay);
            ax = fmaf(blo(v6), w6, ax); ay = fmaf(bhi(v6), w6, ay);
            ax = fmaf(blo(v7), w7, ax); ay = fmaf(bhi(v7), w7, ay);
        }
    }
    float2 bb = *(const float2*)&bias[lane * 2];
    ax += bb.x; ay += bb.y;
    if (RELU){ ax = fmaxf(ax, 0.f); ay = fmaxf(ay, 0.f); }
    if (OUTBF16){
        unsigned o = (unsigned)f2b(ax) | ((unsigned)f2b(ay) << 16);
        ((unsigned*)OUTp)[(size_t)wv * 64 + lane] = o;
    } else {
        float2 o = {ax, ay};
        *(float2*)&((float*)OUTp)[(size_t)wv * FF + lane * 2] = o;
    }
}

// 40-wide bf16 gather + bias + log_softmax. One wave per row; lanes 0..19, 2 cols each.
__global__ __launch_bounds__(256) void k_agg40lsm(const unsigned short* __restrict__ H40,
                                                  const float* __restrict__ dinv,
                                                  const int* __restrict__ rowptr,
                                                  const int2* __restrict__ ew,
                                                  const float* __restrict__ bias,
                                                  float* __restrict__ OUT){
    int wv = (blockIdx.x * 256 + threadIdx.x) >> 6;
    int lane = threadIdx.x & 63;
    if (wv >= NN) return;
    int r0 = rowptr[wv], r1 = rowptr[wv + 1];
    float dv = dinv[wv];
    float sw = dv * dv;
    const bool act = lane < (NC / 2);
    float ax = 0.f, ay = 0.f;
    if (act){
        unsigned hv = ((const unsigned*)(H40 + (size_t)wv * NC))[lane];
        ax = blo(hv) * sw; ay = bhi(hv) * sw;
    }
    for (int base = r0; base < r1; base += 64){
        int len = r1 - base; if (len > 64) len = 64;
        int2 ev = make_int2(0, 0);
        if (lane < len) ev = ew[base + lane];
        int sv = ev.x; float wl = __int_as_float(ev.y);
        for (int j = 0; j < len; j += 8){
            int s0=__shfl(sv,j+0), s1=__shfl(sv,j+1), s2=__shfl(sv,j+2), s3=__shfl(sv,j+3);
            int s4=__shfl(sv,j+4), s5=__shfl(sv,j+5), s6=__shfl(sv,j+6), s7=__shfl(sv,j+7);
            float w0=__shfl(wl,j+0), w1=__shfl(wl,j+1), w2=__shfl(wl,j+2), w3=__shfl(wl,j+3);
            float w4=__shfl(wl,j+4), w5=__shfl(wl,j+5), w6=__shfl(wl,j+6), w7=__shfl(wl,j+7);
            if (act){
                unsigned v0 = ((const unsigned*)(H40 + (size_t)s0 * NC))[lane];
                unsigned v1 = ((const unsigned*)(H40 + (size_t)s1 * NC))[lane];
                unsigned v2 = ((const unsigned*)(H40 + (size_t)s2 * NC))[lane];
                unsigned v3 = ((const unsigned*)(H40 + (size_t)s3 * NC))[lane];
                unsigned v4 = ((const unsigned*)(H40 + (size_t)s4 * NC))[lane];
                unsigned v5 = ((const unsigned*)(H40 + (size_t)s5 * NC))[lane];
                unsigned v6 = ((const unsigned*)(H40 + (size_t)s6 * NC))[lane];
                unsigned v7 = ((const unsigned*)(H40 + (size_t)s7 * NC))[lane];
                ax = fmaf(blo(v0), w0, ax); ay = fmaf(bhi(v0), w0, ay);
                ax = fmaf(blo(v1), w1, ax); ay = fmaf(bhi(v1), w1, ay);
                ax = fmaf(blo(v2), w2, ax); ay = fmaf(bhi(v2), w2, ay);
                ax = fmaf(blo(v3), w3, ax); ay = fmaf(bhi(v3), w3, ay);
                ax = fmaf(blo(v4), w4, ax); ay = fmaf(bhi(v4), w4, ay);
                ax = fmaf(blo(v5), w5, ax); ay = fmaf(bhi(v5), w5, ay);
                ax = fmaf(blo(v6), w6, ax); ay = fmaf(bhi(v6), w6, ay);
                ax = fmaf(blo(v7), w7, ax); ay = fmaf(bhi(v7), w7, ay);
            }
        }
    }
    float val0 = -INFINITY, val1 = -INFINITY;
    if (act){
        float2 bb = *(const float2*)&bias[lane * 2];
        val0 = ax + bb.x; val1 = ay + bb.y;
    }
    float m = fmaxf(val0, val1);
#pragma unroll
    for (int off = 32; off; off >>= 1) m = fmaxf(m, __shfl_xor(m, off));
    float ex = act ? (expf(val0 - m) + expf(val1 - m)) : 0.f;
    float sm = ex;
#pragma unroll
    for (int off = 32; off; off >>= 1) sm += __shfl_xor(sm, off);
    float ls = logf(sm);
    if (act){
        float2 o = {val0 - m - ls, val1 - m - ls};
        *(float2*)&OUT[(size_t)wv * NC + lane * 2] = o;
    }
}

// ================= launch =================

extern "C" void kernel_launch(void* const* d_in, const int* in_sizes, int n_in,
                              void* d_out, int out_size, void* d_ws, size_t ws_size,
                              hipStream_t stream){
    const float* x  = (const float*)d_in[0];
    const int*   ei = (const int*)d_in[1];
    const float* W1 = (const float*)d_in[2];
    const float* b1 = (const float*)d_in[3];
    const float* W2 = (const float*)d_in[4];
    const float* b2 = (const float*)d_in[5];
    const float* W3 = (const float*)d_in[6];
    const float* b3 = (const float*)d_in[7];
    const int* S = ei;
    const int* D = ei + NE;
    float* out = (float*)d_out;

    // workspace layout (units of 4B floats); peak ~98 MB
    float* ws     = (float*)d_ws;
    float* dinv   = ws;                                       // NN (pad 169344)
    int*   rowptr = (int*)(ws + 169344);                      // NN+1 = 169344
    int*   pos    = (int*)(ws + 338688);                      // NN (pad 169344)
    int*   bsum   = (int*)(ws + 508032);                      // pad 512
    int2*  ew     = (int2*)(ws + 508544);                     // NE int2 (pad to 2841088)
    unsigned short* Wt1 = (unsigned short*)(ws + 2841088);    // 8192 f
    unsigned short* Wt2 = (unsigned short*)(ws + 2849280);    // 8192 f
    unsigned short* Hb  = (unsigned short*)(ws + 2857472);    // NN*128 bf16 = 10837952 f
    unsigned short* H40 = (unsigned short*)(ws + 2857472);    // NN*40 bf16 overlay (Hb dead)
    unsigned short* B1b = (unsigned short*)(ws + 13695424);   // NN*128 bf16
    unsigned short* B2b = (unsigned short*)(ws + 13695424);   // overlay (B1b dead after gemm2)
    // end: 13695424 + 10837952 = 24533376 floats = 98.1 MB

    dim3 blk(256);
    const int gN  = cdiv(NN, 256);
    const int gE4 = cdiv(NE, 1024);                           // 4 edges/thread
    const int gW  = cdiv(NN, 4);                              // 4 waves/block
    const int gM  = cdiv(NN, 64);                             // MFMA gemm blocks

    // ---- CSR build + weight conversion ----
    k_zeroi      <<<gN, blk, 0, stream>>>(pos, NN);
    k_hist       <<<gE4, blk, 0, stream>>>(D, pos, NE);
    k_dinv       <<<gN, blk, 0, stream>>>(dinv, pos, NN);
    k_blksum     <<<NB_SCAN, blk, 0, stream>>>(pos, bsum);
    k_scan_root  <<<1, blk, 0, stream>>>(bsum, NB_SCAN);
    k_scan_final <<<NB_SCAN, blk, 0, stream>>>(pos, bsum, rowptr);
    k_fillpos    <<<gN, blk, 0, stream>>>(rowptr, pos, NN);
    k_scatter    <<<gE4, blk, 0, stream>>>(S, D, dinv, pos, ew, NE);
    k_cvtW       <<<64, blk, 0, stream>>>(W1, Wt1);
    k_cvtW       <<<64, blk, 0, stream>>>(W2, Wt2);

    // ---- layer 1: Hb = bf16(x@W1) ; B1b = bf16(relu(Ahat*Hb + b1)) ----
    k_gemm128m<1> <<<gM, blk, 0, stream>>>(x, Wt1, Hb, NN);
    k_agg128<1,1> <<<gW, blk, 0, stream>>>(Hb, dinv, rowptr, ew, b1, B1b);

    // ---- layer 2: Hb = bf16(B1b@W2) ; B2b = bf16(Ahat*Hb + b2) ----
    k_gemm128m<0> <<<gM, blk, 0, stream>>>(B1b, Wt2, Hb, NN);
    k_agg128<0,1> <<<gW, blk, 0, stream>>>(Hb, dinv, rowptr, ew, b2, B2b);

    // ---- layer 3: H40 = bf16(B2b@W3) ; out = log_softmax(Ahat*H40 + b3) ----
    k_gemm40 <<<cdiv(NN, 32), blk, 0, stream>>>(B2b, W3, H40, NN);
    k_agg40lsm <<<gW, blk, 0, stream>>>(H40, dinv, rowptr, ew, b3, out);
}

// Round 11
// 556.764 us; speedup vs baseline: 8.3113x; 1.1141x over previous
//
#include <hip/hip_runtime.h>
#include <math.h>

#define NN 169343
#define NE 1166243
#define FF 128
#define NC 40
#define NB_SCAN 166   // cdiv(NN, 1024)

static inline int cdiv(long long a, long long b){ return (int)((a + b - 1) / b); }

typedef __attribute__((ext_vector_type(8))) short short8;
typedef __attribute__((ext_vector_type(4))) float f32x4;

// bf16 helpers (RNE pack, shift unpack)
__device__ __forceinline__ unsigned short f2b(float f){
    unsigned u = __float_as_uint(f);
    return (unsigned short)((u + 0x7fffu + ((u >> 16) & 1u)) >> 16);
}
__device__ __forceinline__ float blo(unsigned v){ return __uint_as_float(v << 16); }
__device__ __forceinline__ float bhi(unsigned v){ return __uint_as_float(v & 0xffff0000u); }
__device__ __forceinline__ float b2f(unsigned short v){ return __uint_as_float((unsigned)v << 16); }

// ================= CSR build =================

__global__ void k_zeroi(int* __restrict__ p, int n){
    int i = blockIdx.x * 256 + threadIdx.x;
    if (i < n) p[i] = 0;
}

// 4 strided edges per thread: independent atomic chains, coalesced reads
__global__ void k_hist(const int* __restrict__ D, int* __restrict__ cnt, int E){
    int base = blockIdx.x * 1024 + threadIdx.x;
#pragma unroll
    for (int j = 0; j < 4; j++){
        int e = base + j * 256;
        if (e < E) atomicAdd(&cnt[D[e]], 1);
    }
}

__global__ void k_dinv(float* __restrict__ dinv, const int* __restrict__ cnt, int n){
    int i = blockIdx.x * 256 + threadIdx.x;
    if (i < n) dinv[i] = rsqrtf((float)(cnt[i] + 1));   // +1 self loop
}

__global__ __launch_bounds__(256) void k_blksum(const int* __restrict__ cnt, int* __restrict__ bsum){
    __shared__ int wsum[4];
    int t = threadIdx.x;
    int base = blockIdx.x * 1024 + t * 4;
    int s = 0;
#pragma unroll
    for (int j = 0; j < 4; j++) if (base + j < NN) s += cnt[base + j];
#pragma unroll
    for (int off = 32; off; off >>= 1) s += __shfl_down(s, off);
    if ((t & 63) == 0) wsum[t >> 6] = s;
    __syncthreads();
    if (t == 0) bsum[blockIdx.x] = wsum[0] + wsum[1] + wsum[2] + wsum[3];
}

__global__ __launch_bounds__(256) void k_scan_root(int* __restrict__ bsum, int nb){
    __shared__ int sh[256];
    int t = threadIdx.x;
    int v = (t < nb) ? bsum[t] : 0;
    sh[t] = v; __syncthreads();
    for (int d = 1; d < 256; d <<= 1){
        int add = (t >= d) ? sh[t - d] : 0;
        __syncthreads();
        sh[t] += add;
        __syncthreads();
    }
    if (t < nb) bsum[t] = sh[t] - v;   // exclusive
}

__global__ __launch_bounds__(256) void k_scan_final(const int* __restrict__ cnt,
                                                    const int* __restrict__ bsumEx,
                                                    int* __restrict__ rowptr){
    __shared__ int sh[256];
    int t = threadIdx.x;
    int base = blockIdx.x * 1024 + t * 4;
    int v0=0,v1=0,v2=0,v3=0;
    if (base + 0 < NN) v0 = cnt[base + 0];
    if (base + 1 < NN) v1 = cnt[base + 1];
    if (base + 2 < NN) v2 = cnt[base + 2];
    if (base + 3 < NN) v3 = cnt[base + 3];
    int tsum = v0 + v1 + v2 + v3;
    sh[t] = tsum; __syncthreads();
    for (int d = 1; d < 256; d <<= 1){
        int add = (t >= d) ? sh[t - d] : 0;
        __syncthreads();
        sh[t] += add;
        __syncthreads();
    }
    int off = sh[t] - tsum + bsumEx[blockIdx.x];
    if (base + 0 < NN) rowptr[base + 0] = off;
    if (base + 1 < NN) rowptr[base + 1] = off + v0;
    if (base + 2 < NN) rowptr[base + 2] = off + v0 + v1;
    if (base + 3 < NN) rowptr[base + 3] = off + v0 + v1 + v2;
}

__global__ void k_fillpos(const int* __restrict__ rowptr, int* __restrict__ pos, int n){
    int i = blockIdx.x * 256 + threadIdx.x;
    if (i < n) pos[i] = rowptr[i];
    if (i == 0) ((int*)rowptr)[NN] = NE;   // sentinel
}

// packed (src, wn) single 8B scattered store; 4 strided edges/thread
__global__ void k_scatter(const int* __restrict__ S, const int* __restrict__ D,
                          const float* __restrict__ dinv, int* __restrict__ pos,
                          int2* __restrict__ ew, int E){
    int base = blockIdx.x * 1024 + threadIdx.x;
#pragma unroll
    for (int j = 0; j < 4; j++){
        int e = base + j * 256;
        if (e < E){
            int s = S[e], d = D[e];
            float wn = dinv[s] * dinv[d];
            int p = atomicAdd(&pos[d], 1);
            ew[p] = make_int2(s, __float_as_int(wn));
        }
    }
}

// W[k][n] fp32 -> Wt[n][k] bf16 (transpose + quantize), 128x128
__global__ void k_cvtW(const float* __restrict__ W, unsigned short* __restrict__ Wt){
    int i = blockIdx.x * 256 + threadIdx.x;     // 16384
    int c = i >> 7, k = i & 127;
    Wt[c * FF + k] = f2b(W[k * FF + c]);
}

// ================= MFMA GEMM: H[M][128] = A[M][128] @ W, bf16 in, fp32 acc, bf16 out ====
// Wt staged in LDS (padded stride 136 -> 2-way-conflict-free ds_read_b128).
// 512 thr = 8 waves, block owns 128 rows; wave: 16 rows x 128 cols.
// A-frag: lane = (row l&15, k-group (l>>4)*8). C/D: col=lane&15, row=(lane>>4)*4+reg.

template<int AFP32>
__global__ __launch_bounds__(512) void k_gemm128m(const void* __restrict__ Ap,
                                                  const unsigned short* __restrict__ Wt,
                                                  unsigned short* __restrict__ Hb, int M){
    __shared__ unsigned short Wl[128 * 136];    // 34.8 KB
    const int tid = threadIdx.x;
    {   // stage 128x128 bf16: thread t -> row t>>2, 32-elem chunk (t&3)*32
        int r = tid >> 2, kb = (tid & 3) * 32;
        const short8* src = (const short8*)(Wt + r * FF + kb);
        short8* dst = (short8*)(&Wl[r * 136 + kb]);
        dst[0] = src[0]; dst[1] = src[1]; dst[2] = src[2]; dst[3] = src[3];
    }
    __syncthreads();
    const int lane = tid & 63;
    const int wid = tid >> 6;                   // 0..7
    const int m0 = blockIdx.x * 128 + wid * 16;
    const int row = m0 + (lane & 15);
    const int kg = (lane >> 4) * 8;
    const bool rowok = row < M;
    f32x4 acc[8] = {};
#pragma unroll
    for (int kk = 0; kk < 4; kk++){
        const int k0 = kk * 32 + kg;
        short8 a = {0,0,0,0,0,0,0,0};
        if (rowok){
            if (AFP32){
                const float* A = (const float*)Ap;
                const float* p = &A[(size_t)row * FF + k0];
                float4 u0 = *(const float4*)p;
                float4 u1 = *(const float4*)(p + 4);
                a[0]=(short)f2b(u0.x); a[1]=(short)f2b(u0.y); a[2]=(short)f2b(u0.z); a[3]=(short)f2b(u0.w);
                a[4]=(short)f2b(u1.x); a[5]=(short)f2b(u1.y); a[6]=(short)f2b(u1.z); a[7]=(short)f2b(u1.w);
            } else {
                const unsigned short* Ab = (const unsigned short*)Ap;
                a = *(const short8*)&Ab[(size_t)row * FF + k0];
            }
        }
#pragma unroll
        for (int n = 0; n < 8; n++){
            short8 b = *(const short8*)&Wl[(n * 16 + (lane & 15)) * 136 + k0];
            acc[n] = __builtin_amdgcn_mfma_f32_16x16x32_bf16(a, b, acc[n], 0, 0, 0);
        }
    }
    const int orow0 = m0 + (lane >> 4) * 4;
    const int ocol = lane & 15;
#pragma unroll
    for (int n = 0; n < 8; n++){
#pragma unroll
        for (int r = 0; r < 4; r++){
            int orow = orow0 + r;
            if (orow < M) Hb[(size_t)orow * FF + n * 16 + ocol] = f2b(acc[n][r]);
        }
    }
}

// ================= GEMM 128x40: bf16 A, fp32 W/math, bf16 out =================

__global__ __launch_bounds__(256) void k_gemm40(const unsigned short* __restrict__ Ab,
                                                const float* __restrict__ W,
                                                unsigned short* __restrict__ H40, int M){
    __shared__ float Wsh[128][40];
    __shared__ float Ash[32][132];
    const int tid = threadIdx.x;
    const int rt = tid >> 3, ct = tid & 7;
    const int cb = ct * 5;
    const int row0 = blockIdx.x * 32;
#pragma unroll
    for (int i = 0; i < 5; i++){
        int q = tid + 256 * i;
        int r = q / 10, c4 = (q % 10) * 4;
        *(float4*)&Wsh[r][c4] = *(const float4*)&W[(size_t)r * NC + c4];
    }
#pragma unroll
    for (int i = 0; i < 4; i++){
        int q = tid + 256 * i; int r = q >> 5, c4 = (q & 31) * 4;
        int gr = row0 + r;
        ushort4 u = {0, 0, 0, 0};
        if (gr < M) u = *(const ushort4*)&Ab[(size_t)gr * FF + c4];
        Ash[r][c4 + 0] = b2f(u.x);
        Ash[r][c4 + 1] = b2f(u.y);
        Ash[r][c4 + 2] = b2f(u.z);
        Ash[r][c4 + 3] = b2f(u.w);
    }
    __syncthreads();
    float acc[5] = {};
    for (int k4 = 0; k4 < 128; k4 += 4){
        float4 a = *(const float4*)&Ash[rt][k4];
#pragma unroll
        for (int j = 0; j < 5; j++){
            acc[j] = fmaf(a.x, Wsh[k4 + 0][cb + j], acc[j]);
            acc[j] = fmaf(a.y, Wsh[k4 + 1][cb + j], acc[j]);
            acc[j] = fmaf(a.z, Wsh[k4 + 2][cb + j], acc[j]);
            acc[j] = fmaf(a.w, Wsh[k4 + 3][cb + j], acc[j]);
        }
    }
    int gr = row0 + rt;
    if (gr < M){
#pragma unroll
        for (int j = 0; j < 5; j++) H40[(size_t)gr * NC + cb + j] = f2b(acc[j]);
    }
}

// ================= CSR gather, bf16 operand, packed-edge prefetch + x8 MLP =================

template<int RELU, int OUTBF16>
__global__ __launch_bounds__(256) void k_agg128(const unsigned short* __restrict__ Hb,
                                                const float* __restrict__ dinv,
                                                const int* __restrict__ rowptr,
                                                const int2* __restrict__ ew,
                                                const float* __restrict__ bias,
                                                void* __restrict__ OUTp){
    int wv = (blockIdx.x * 256 + threadIdx.x) >> 6;
    int lane = threadIdx.x & 63;
    if (wv >= NN) return;                             // wave-uniform exit
    int r0 = rowptr[wv], r1 = rowptr[wv + 1];
    float dv = dinv[wv];
    float sw = dv * dv;
    unsigned hv = ((const unsigned*)(Hb + (size_t)wv * FF))[lane];
    float ax = blo(hv) * sw, ay = bhi(hv) * sw;
    for (int base = r0; base < r1; base += 64){
        int len = r1 - base; if (len > 64) len = 64;
        int2 ev = make_int2(0, 0);
        if (lane < len) ev = ew[base + lane];
        int sv = ev.x; float wl = __int_as_float(ev.y);
        for (int j = 0; j < len; j += 8){
            int s0=__shfl(sv,j+0), s1=__shfl(sv,j+1), s2=__shfl(sv,j+2), s3=__shfl(sv,j+3);
            int s4=__shfl(sv,j+4), s5=__shfl(sv,j+5), s6=__shfl(sv,j+6), s7=__shfl(sv,j+7);
            float w0=__shfl(wl,j+0), w1=__shfl(wl,j+1), w2=__shfl(wl,j+2), w3=__shfl(wl,j+3);
            float w4=__shfl(wl,j+4), w5=__shfl(wl,j+5), w6=__shfl(wl,j+6), w7=__shfl(wl,j+7);
            unsigned v0 = ((const unsigned*)(Hb + (size_t)s0 * FF))[lane];
            unsigned v1 = ((const unsigned*)(Hb + (size_t)s1 * FF))[lane];
            unsigned v2 = ((const unsigned*)(Hb + (size_t)s2 * FF))[lane];
            unsigned v3 = ((const unsigned*)(Hb + (size_t)s3 * FF))[lane];
            unsigned v4 = ((const unsigned*)(Hb + (size_t)s4 * FF))[lane];
            unsigned v5 = ((const unsigned*)(Hb + (size_t)s5 * FF))[lane];
            unsigned v6 = ((const unsigned*)(Hb + (size_t)s6 * FF))[lane];
            unsigned v7 = ((const unsigned*)(Hb + (size_t)s7 * FF))[lane];
            ax = fmaf(blo(v0), w0, ax); ay = fmaf(bhi(v0), w0, ay);
            ax = fmaf(blo(v1), w1, ax); ay = fmaf(bhi(v1), w1, ay);
            ax = fmaf(blo(v2), w2, ax); ay = fmaf(bhi(v2), w2, ay);
            ax = fmaf(blo(v3), w3, ax); ay = fmaf(bhi(v3), w3, ay);
            ax = fmaf(blo(v4), w4, ax); ay = fmaf(bhi(v4), w4, ay);
            ax = fmaf(blo(v5), w5, ax); ay = fmaf(bhi(v5), w5, ay);
            ax = fmaf(blo(v6), w6, ax); ay = fmaf(bhi(v6), w6, ay);
            ax = fmaf(blo(v7), w7, ax); ay = fmaf(bhi(v7), w7, ay);
        }
    }
    float2 bb = *(const float2*)&bias[lane * 2];
    ax += bb.x; ay += bb.y;
    if (RELU){ ax = fmaxf(ax, 0.f); ay = fmaxf(ay, 0.f); }
    if (OUTBF16){
        unsigned o = (unsigned)f2b(ax) | ((unsigned)f2b(ay) << 16);
        ((unsigned*)OUTp)[(size_t)wv * 64 + lane] = o;
    } else {
        float2 o = {ax, ay};
        *(float2*)&((float*)OUTp)[(size_t)wv * FF + lane * 2] = o;
    }
}

// 40-wide bf16 gather + bias + log_softmax. One wave per row.
// Two 32-lane edge-groups (g=lane>>5) process alternate edges; 20 col-pair lanes each.
__global__ __launch_bounds__(256) void k_agg40lsm(const unsigned short* __restrict__ H40,
                                                  const float* __restrict__ dinv,
                                                  const int* __restrict__ rowptr,
                                                  const int2* __restrict__ ew,
                                                  const float* __restrict__ bias,
                                                  float* __restrict__ OUT){
    int wv = (blockIdx.x * 256 + threadIdx.x) >> 6;
    int lane = threadIdx.x & 63;
    if (wv >= NN) return;
    int r0 = rowptr[wv], r1 = rowptr[wv + 1];
    const int g = lane >> 5;            // edge-group 0/1
    const int c = lane & 31;            // col-pair id within group
    const bool act = c < (NC / 2);
    float ax = 0.f, ay = 0.f;
    for (int base = r0; base < r1; base += 64){
        int len = r1 - base; if (len > 64) len = 64;
        int2 ev = make_int2(0, 0);
        if (lane < len) ev = ew[base + lane];
        int sv = ev.x; float wl = __int_as_float(ev.y);
        for (int j = 0; j < len; j += 8){
            // group g handles edges j+g, j+2+g, j+4+g, j+6+g (idx <= 63 always)
            int i0 = j + g, i1 = j + 2 + g, i2 = j + 4 + g, i3 = j + 6 + g;
            int s0=__shfl(sv,i0), s1=__shfl(sv,i1), s2=__shfl(sv,i2), s3=__shfl(sv,i3);
            float w0=__shfl(wl,i0), w1=__shfl(wl,i1), w2=__shfl(wl,i2), w3=__shfl(wl,i3);
            if (act){
                unsigned v0 = ((const unsigned*)(H40 + (size_t)s0 * NC))[c];
                unsigned v1 = ((const unsigned*)(H40 + (size_t)s1 * NC))[c];
                unsigned v2 = ((const unsigned*)(H40 + (size_t)s2 * NC))[c];
                unsigned v3 = ((const unsigned*)(H40 + (size_t)s3 * NC))[c];
                ax = fmaf(blo(v0), w0, ax); ay = fmaf(bhi(v0), w0, ay);
                ax = fmaf(blo(v1), w1, ax); ay = fmaf(bhi(v1), w1, ay);
                ax = fmaf(blo(v2), w2, ax); ay = fmaf(bhi(v2), w2, ay);
                ax = fmaf(blo(v3), w3, ax); ay = fmaf(bhi(v3), w3, ay);
            }
        }
    }
    // combine the two edge-groups
    ax += __shfl_xor(ax, 32);
    ay += __shfl_xor(ay, 32);
    float val0 = -INFINITY, val1 = -INFINITY;
    if (lane < (NC / 2)){
        float dv = dinv[wv];
        float sw = dv * dv;
        unsigned hv = ((const unsigned*)(H40 + (size_t)wv * NC))[lane];
        float2 bb = *(const float2*)&bias[lane * 2];
        val0 = ax + blo(hv) * sw + bb.x;
        val1 = ay + bhi(hv) * sw + bb.y;
    }
    float m = fmaxf(val0, val1);
#pragma unroll
    for (int off = 32; off; off >>= 1) m = fmaxf(m, __shfl_xor(m, off));
    float ex = (lane < (NC / 2)) ? (expf(val0 - m) + expf(val1 - m)) : 0.f;
    float sm = ex;
#pragma unroll
    for (int off = 32; off; off >>= 1) sm += __shfl_xor(sm, off);
    float ls = logf(sm);
    if (lane < (NC / 2)){
        float2 o = {val0 - m - ls, val1 - m - ls};
        *(float2*)&OUT[(size_t)wv * NC + lane * 2] = o;
    }
}

// ================= launch =================

extern "C" void kernel_launch(void* const* d_in, const int* in_sizes, int n_in,
                              void* d_out, int out_size, void* d_ws, size_t ws_size,
                              hipStream_t stream){
    const float* x  = (const float*)d_in[0];
    const int*   ei = (const int*)d_in[1];
    const float* W1 = (const float*)d_in[2];
    const float* b1 = (const float*)d_in[3];
    const float* W2 = (const float*)d_in[4];
    const float* b2 = (const float*)d_in[5];
    const float* W3 = (const float*)d_in[6];
    const float* b3 = (const float*)d_in[7];
    const int* S = ei;
    const int* D = ei + NE;
    float* out = (float*)d_out;

    // workspace layout (units of 4B floats); peak ~98 MB
    float* ws     = (float*)d_ws;
    float* dinv   = ws;                                       // NN (pad 169344)
    int*   rowptr = (int*)(ws + 169344);                      // NN+1 = 169344
    int*   pos    = (int*)(ws + 338688);                      // NN (pad 169344)
    int*   bsum   = (int*)(ws + 508032);                      // pad 512
    int2*  ew     = (int2*)(ws + 508544);                     // NE int2 (pad to 2841088)
    unsigned short* Wt1 = (unsigned short*)(ws + 2841088);    // 8192 f
    unsigned short* Wt2 = (unsigned short*)(ws + 2849280);    // 8192 f
    unsigned short* Hb  = (unsigned short*)(ws + 2857472);    // NN*128 bf16 = 10837952 f
    unsigned short* H40 = (unsigned short*)(ws + 2857472);    // NN*40 bf16 overlay (Hb dead)
    unsigned short* B1b = (unsigned short*)(ws + 13695424);   // NN*128 bf16
    unsigned short* B2b = (unsigned short*)(ws + 13695424);   // overlay (B1b dead after gemm2)
    // end: 13695424 + 10837952 = 24533376 floats = 98.1 MB

    dim3 blk(256);
    dim3 blk512(512);
    const int gN  = cdiv(NN, 256);
    const int gE4 = cdiv(NE, 1024);                           // 4 edges/thread
    const int gW  = cdiv(NN, 4);                              // 4 waves/block
    const int gM  = cdiv(NN, 128);                            // MFMA gemm blocks (128 rows each)

    // ---- CSR build + weight conversion ----
    k_zeroi      <<<gN, blk, 0, stream>>>(pos, NN);
    k_hist       <<<gE4, blk, 0, stream>>>(D, pos, NE);
    k_dinv       <<<gN, blk, 0, stream>>>(dinv, pos, NN);
    k_blksum     <<<NB_SCAN, blk, 0, stream>>>(pos, bsum);
    k_scan_root  <<<1, blk, 0, stream>>>(bsum, NB_SCAN);
    k_scan_final <<<NB_SCAN, blk, 0, stream>>>(pos, bsum, rowptr);
    k_fillpos    <<<gN, blk, 0, stream>>>(rowptr, pos, NN);
    k_scatter    <<<gE4, blk, 0, stream>>>(S, D, dinv, pos, ew, NE);
    k_cvtW       <<<64, blk, 0, stream>>>(W1, Wt1);
    k_cvtW       <<<64, blk, 0, stream>>>(W2, Wt2);

    // ---- layer 1: Hb = bf16(x@W1) ; B1b = bf16(relu(Ahat*Hb + b1)) ----
    k_gemm128m<1> <<<gM, blk512, 0, stream>>>(x, Wt1, Hb, NN);
    k_agg128<1,1> <<<gW, blk, 0, stream>>>(Hb, dinv, rowptr, ew, b1, B1b);

    // ---- layer 2: Hb = bf16(B1b@W2) ; B2b = bf16(Ahat*Hb + b2) ----
    k_gemm128m<0> <<<gM, blk512, 0, stream>>>(B1b, Wt2, Hb, NN);
    k_agg128<0,1> <<<gW, blk, 0, stream>>>(Hb, dinv, rowptr, ew, b2, B2b);

    // ---- layer 3: H40 = bf16(B2b@W3) ; out = log_softmax(Ahat*H40 + b3) ----
    k_gemm40 <<<cdiv(NN, 32), blk, 0, stream>>>(B2b, W3, H40, NN);
    k_agg40lsm <<<gW, blk, 0, stream>>>(H40, dinv, rowptr, ew, b3, out);
}